// Round 7
// baseline (1182.799 us; speedup 1.0000x reference)
//
#include <hip/hip_runtime.h>

// Equivariant graph attention (Transformer_41480794145180) — fp32 throughout.
//
// Pipeline (all on `stream`):
//   k_zero/k_hist/k_scan/k_fill : build CSR of edges grouped by dst node
//   k_dhist/k_dscan/k_dfill     : counting-sort nodes by degree (descending)
//   k_gather: permute xattr/eattr/cutoff/esrc into CSR slot order
//   k_nodeA : per-node A fragments (lane-contiguous layout)
//   k_fused : wave-per-node (degree-sorted), SINGLE edge pass:
//             k-MLP -> logits -> expw (regs) ; v-MLP -> sqrt(expw)*v accum ;
//             z accumulated in regs; final rescale by 1/sqrt(z) ; wave agg ;
//             fused output linear -> out
//
// R7 (R6 post-mortem: degree-sort worked [VALU 41%, 1084us]; remaining cost
// is algorithmic duplication between the two edge passes):
//  - sqrt-factorization: sa = sqrt(expw/z) = sqrt(expw)/sqrt(z), and
//    agg = (1/sqrt(z_h)) * sum_e sqrt(expw_e)*v_e  — normalization commutes
//    with the sum, so ONE pass per node computes everything. Eliminates the
//    sa round-trip (10MB), the second pass over edge data (~30MB), the
//    expws LDS buffer, the z re-scan, and one weight staging.
//  - expw broadcast lane0..15 -> all lanes via __shfl (no LDS).

constexpr float INV3    = 0.57735026918962576f;  // 1/sqrt(3)
constexpr float INV_SQ8 = 0.35355339059327373f;  // 1/sqrt(N_BASIS=8)
constexpr float INV_HID = 0.125f;                // 1/sqrt(HID=64)
constexpr float INV_FAN = 0.015625f;             // 1/sqrt(4*32*32)
constexpr float INV_L   = 0.125f;                // 1/sqrt(2*MUL=64)
constexpr int   MAXD    = 128;                   // max in-degree (Poisson(32), max~70)

// jax.nn.gelu default (approximate=True, tanh form)
__device__ __forceinline__ float gelu_tanh(float x) {
  float u = 0.7978845608028654f * (x + 0.044715f * x * x * x);
  float e = __expf(2.0f * u);            // e=inf / e=0 limits are exact
  return x * (1.0f - 1.0f / (e + 1.0f)); // = 0.5x(1+tanh(u))
}

// ---------------- CSR build ----------------
__global__ void k_zero(int* __restrict__ p, int n) {
  int i = blockIdx.x * 256 + threadIdx.x;
  if (i < n) p[i] = 0;
}

__global__ void k_hist(const int* __restrict__ dst, int* __restrict__ cnt, int E) {
  int e = blockIdx.x * 256 + threadIdx.x;
  if (e < E) atomicAdd(&cnt[dst[e]], 1);
}

// single-block exclusive scan over N counts -> rowptr[0..N]
__global__ __launch_bounds__(256) void k_scan(const int* __restrict__ cnt,
                                              int* __restrict__ rowptr, int N) {
  __shared__ int wsum[4];
  __shared__ int woff[4];
  __shared__ int carry;
  int t = threadIdx.x, wave = t >> 6, lane = t & 63;
  if (t == 0) { carry = 0; rowptr[0] = 0; }
  __syncthreads();
  for (int base = 0; base < N; base += 256) {
    int i = base + t;
    int inc = (i < N) ? cnt[i] : 0;
#pragma unroll
    for (int off = 1; off < 64; off <<= 1) {
      int y = __shfl_up(inc, off, 64);
      if (lane >= off) inc += y;
    }
    if (lane == 63) wsum[wave] = inc;
    __syncthreads();
    if (t == 0) {
      int r = 0;
      for (int w = 0; w < 4; w++) { woff[w] = r; r += wsum[w]; }
    }
    __syncthreads();
    int incl = inc + woff[wave] + carry;
    if (i < N) rowptr[i + 1] = incl;
    __syncthreads();
    if (t == 255) carry = incl;  // padded lanes add 0, so this is the chunk total
    __syncthreads();
  }
}

__global__ void k_fill(const int* __restrict__ dst, const int* __restrict__ rowptr,
                       int* __restrict__ cursor, int* __restrict__ csr, int E) {
  int e = blockIdx.x * 256 + threadIdx.x;
  if (e < E) {
    int d = dst[e];
    int s = atomicAdd(&cursor[d], 1);
    csr[rowptr[d] + s] = e;
  }
}

// ---------------- degree counting sort (descending) ----------------
__global__ void k_dhist(const int* __restrict__ rowptr, int* __restrict__ dbin, int N) {
  int n = blockIdx.x * 256 + threadIdx.x;
  if (n < N) {
    int deg = rowptr[n + 1] - rowptr[n];
    atomicAdd(&dbin[min(deg, 127)], 1);
  }
}

__global__ void k_dscan(const int* __restrict__ dbin, int* __restrict__ doff) {
  if (threadIdx.x == 0 && blockIdx.x == 0) {
    int r = 0;
    for (int d = 127; d >= 0; --d) { doff[d] = r; r += dbin[d]; }
  }
}

__global__ void k_dfill(const int* __restrict__ rowptr, const int* __restrict__ doff,
                        int* __restrict__ dcur, int* __restrict__ nperm, int N) {
  int n = blockIdx.x * 256 + threadIdx.x;
  if (n < N) {
    int d = min(rowptr[n + 1] - rowptr[n], 127);
    int p = doff[d] + atomicAdd(&dcur[d], 1);
    nperm[p] = n;
  }
}

// permute edge arrays into CSR slot order (coalesced writes, random reads)
__global__ __launch_bounds__(256) void k_gather(
    const int* __restrict__ csr, const int* __restrict__ esrc,
    const float* __restrict__ xattr, const float* __restrict__ eattr,
    const float* __restrict__ cutoff,
    float* __restrict__ xc, float* __restrict__ ec, float* __restrict__ cc,
    int* __restrict__ srcc, int E) {
  int p = blockIdx.x * 256 + threadIdx.x;
  if (p >= E) return;
  int e = csr[p];
  srcc[p] = esrc[e];
  cc[p] = cutoff[e];
  ((float4*)ec)[p] = ((const float4*)eattr)[e];
  const float4* xs = (const float4*)xattr + (size_t)e * 2;
  float4* xd = (float4*)xc + (size_t)p * 2;
  xd[0] = xs[0]; xd[1] = xs[1];
}

// ---------------- per-node A precompute ----------------
// A layout per node (1024 f32), lane-contiguous:
//   A0[32][4] (v,h) | A1[32][4] | A2[32][4][3] (v,h,d) | A3[32][4][3]
__global__ __launch_bounds__(256) void k_nodeA(const float* __restrict__ node_f,
                                               const float* __restrict__ Wdot,
                                               float* __restrict__ A, int N) {
  __shared__ float Wd[16384];     // 64 KiB: W_dot[4][4][32][32]
  __shared__ float nfs[32 * 128]; // 16 KiB: 32 nodes' features
  int t = threadIdx.x;
  for (int i = t; i < 16384; i += 256) Wd[i] = Wdot[i];
  int n0 = blockIdx.x * 32;
  int nEnd = min(32, N - n0);
  for (int i = t; i < nEnd * 128; i += 256) nfs[i] = node_f[n0 * 128 + i];
  __syncthreads();
  for (int nn = 0; nn < nEnd; ++nn) {
    const float* nf = &nfs[nn * 128];
    float* An = &A[(n0 + nn) * 1024];
#pragma unroll
    for (int k = 0; k < 4; k++) {
      int o = t + k * 256;  // branch below is uniform per k (no divergence)
      float acc = 0.f;
      int idx;
      if (o < 256) {        // A0 / A1 : scalar q
        int term = o >> 7, h = (o >> 5) & 3, v = o & 31;
        const float* W = &Wd[term * 4096 + h * 1024 + v];
#pragma unroll
        for (int u = 0; u < 32; u++) acc += W[u * 32] * nf[u];
        idx = term * 128 + v * 4 + h;
      } else {              // A2 / A3 : vector q
        int r = o - 256;
        int term = r / 384;                 // 0,1 -> A2,A3
        int rr = r % 384;
        int h = rr / 96, q = rr % 96, v = q / 3, d = q - 3 * (q / 3);
        const float* W = &Wd[(term + 2) * 4096 + h * 1024 + v];
#pragma unroll
        for (int u = 0; u < 32; u++) acc += W[u * 32] * nf[32 + u * 3 + d];
        idx = 256 + term * 384 + v * 12 + h * 3 + d;
      }
      An[idx] = acc;
    }
  }
}

// ---------------- fused edge pass (wave-per-node, degree-sorted) ----------------
__global__ __launch_bounds__(256) void k_fused(
    const int* __restrict__ rowptr,
    const int* __restrict__ nperm,     // degree-sorted node ids
    const int* __restrict__ srcc,      // E, CSR order
    const float* __restrict__ xc,      // E x 8, CSR order
    const float* __restrict__ ec,      // E x 4, CSR order
    const float* __restrict__ cc,      // E, CSR order
    const float* __restrict__ node_f,  // N x 128
    const float* __restrict__ wk1, const float* __restrict__ bk1,
    const float* __restrict__ wk2,
    const float* __restrict__ wv1, const float* __restrict__ bv1,
    const float* __restrict__ wv2,
    const float* __restrict__ Wls, const float* __restrict__ Wlv,  // 64x32 each
    const float* __restrict__ A,       // N x 1024 (lane-contiguous layout)
    float* __restrict__ out,           // N x 128
    int N)
{
  __shared__ __align__(16) float w1k[512];
  __shared__ __align__(16) float w1v[512];
  __shared__ float b1k[64], b1v[64];
  __shared__ __align__(16) float wqk[16][128][4];  // wq[l/4][j][l%4] = wk2[l][j]
  __shared__ __align__(16) float wqv[16][128][4];
  __shared__ __align__(16) float Hs[4][4][64];     // [wave][edge][l] — wave-private
  __shared__ float aggv[4][256];  // [wave][ch']: ch'=u (s) | 64+d*64+u (v)

  int t = threadIdx.x;
  int wave = t >> 6, lane = t & 63;
  for (int i = t; i < 512; i += 256) { w1k[i] = wk1[i]; w1v[i] = wv1[i]; }
  if (t < 64) { b1k[t] = bk1[t]; b1v[t] = bv1[t]; }
  for (int i = t; i < 8192; i += 256) {
    int l = i >> 7, j = i & 127;
    wqk[l >> 2][j][l & 3] = wk2[i];
    wqv[l >> 2][j][l & 3] = wv2[i];
  }
  __syncthreads();  // the only barrier

  int idx = blockIdx.x * 4 + wave;
  if (idx >= N) return;
  int n = nperm[idx];
  int row0 = rowptr[n];
  int deg = min(rowptr[n + 1] - row0, MAXD);

  int v = lane & 31;
  bool hi = lane >= 32;
  int hh = v >> 3;           // head of channel v (m = MUL/H = 8)
  int kk = (lane >> 2) & 3;  // the edge index this lane's folded sum lands on

  // A fragments in registers (attention bilinear form of the dst node)
  float aS[4], aV[12];
  {
    const float* Ab = A + (size_t)n * 1024;
    const float* ps = Ab + (hi ? 128 : 0) + v * 4;
    float4 t0 = *(const float4*)ps;
    aS[0] = t0.x; aS[1] = t0.y; aS[2] = t0.z; aS[3] = t0.w;
    const float* pv = Ab + (hi ? 640 : 256) + v * 12;
    float4 u0 = *(const float4*)pv;
    float4 u1 = *(const float4*)(pv + 4);
    float4 u2 = *(const float4*)(pv + 8);
    aV[0] = u0.x; aV[1] = u0.y; aV[2]  = u0.z; aV[3]  = u0.w;
    aV[4] = u1.x; aV[5] = u1.y; aV[6]  = u1.z; aV[7]  = u1.w;
    aV[8] = u2.x; aV[9] = u2.y; aV[10] = u2.z; aV[11] = u2.w;
  }

  float accS = 0.f, acc0 = 0.f, acc1 = 0.f, acc2 = 0.f;
  float zacc = 0.f;  // lanes 0..15: partial z for (kk, h2=lane&3)

  if (deg > 0) {
    int iters = (deg + 3) >> 2;
    for (int it = 0; it < iters; ++it) {
      int sb = it * 4;
      int slot[4]; int sp[4]; bool val[4];
#pragma unroll
      for (int k = 0; k < 4; k++) {
        val[k] = (sb + k) < deg;
        slot[k] = row0 + min(sb + k, deg - 1);
      }
#pragma unroll
      for (int k = 0; k < 4; k++) sp[k] = srcc[slot[k]];  // streaming (L1)
      float4 ya[4]; float cf[4]; float s0[4], s1[4], s2[4];
#pragma unroll
      for (int k = 0; k < 4; k++) {
        ya[k] = ((const float4*)ec)[slot[k]];
        cf[k] = cc[slot[k]];
        const float* nf = &node_f[(size_t)sp[k] * 128];
        if (!hi) { s0[k] = nf[v]; s1[k] = 0.f; s2[k] = 0.f; }
        else     { s0[k] = nf[32 + v * 3]; s1[k] = nf[33 + v * 3]; s2[k] = nf[34 + v * 3]; }
      }
      // ---- k-MLP: hidden layer, lane computes h_l for 4 edges ----
      float h[4];
#pragma unroll
      for (int k = 0; k < 4; k++) {
        const float4* xp = (const float4*)xc + (size_t)slot[k] * 2;
        float4 xa = xp[0], xb = xp[1];
        float acc = xa.x * w1k[lane]       + xa.y * w1k[64 + lane]
                  + xa.z * w1k[128 + lane] + xa.w * w1k[192 + lane]
                  + xb.x * w1k[256 + lane] + xb.y * w1k[320 + lane]
                  + xb.z * w1k[384 + lane] + xb.w * w1k[448 + lane];
        h[k] = gelu_tanh(acc * INV_SQ8 + b1k[lane]);
      }
#pragma unroll
      for (int k = 0; k < 4; k++) Hs[wave][k][lane] = h[k];  // wave-private
      float a0[4] = {0, 0, 0, 0}, a1[4] = {0, 0, 0, 0};
#pragma unroll
      for (int q = 0; q < 16; q++) {
        float4 wA = *(const float4*)&wqk[q][lane][0];
        float4 wB = *(const float4*)&wqk[q][lane + 64][0];
#pragma unroll
        for (int k = 0; k < 4; k++) {
          float4 hq = *(const float4*)&Hs[wave][k][q * 4];
          a0[k] += hq.x * wA.x + hq.y * wA.y + hq.z * wA.z + hq.w * wA.w;
          a1[k] += hq.x * wB.x + hq.y * wB.y + hq.z * wB.z + hq.w * wB.w;
        }
      }
      // ---- attention logits, folded reduce, expw ----
      float p[16];
#pragma unroll
      for (int k = 0; k < 4; k++) {
        float ys = ya[k].x, yv0 = ya[k].y, yv1 = ya[k].z, yv2 = ya[k].w;
        float wj0 = a0[k] * INV_HID, wj1 = a1[k] * INV_HID;
        if (!hi) {  // lanes 0..31: k0 (w row 0) + kv0 (w row 2)
          float k0 = wj0 * s0[k] * ys;
          float kb = INV3 * wj1 * s0[k];
#pragma unroll
          for (int h2 = 0; h2 < 4; h2++)
            p[k * 4 + h2] = aS[h2] * k0 +
                kb * (aV[h2 * 3] * yv0 + aV[h2 * 3 + 1] * yv1 + aV[h2 * 3 + 2] * yv2);
        } else {    // lanes 32..63: k1 (w row 1) + kv1 (w row 3)
          float dotv = s0[k] * yv0 + s1[k] * yv1 + s2[k] * yv2;
          float k1 = wj0 * dotv * INV3;
          float kc = INV3 * wj1 * ys;
#pragma unroll
          for (int h2 = 0; h2 < 4; h2++)
            p[k * 4 + h2] = aS[h2] * k1 +
                kc * (aV[h2 * 3] * s0[k] + aV[h2 * 3 + 1] * s1[k] + aV[h2 * 3 + 2] * s2[k]);
        }
      }
      // folded butterfly: 16 per-lane values -> full sums, keyed by lane&15
      bool fb0 = (lane & 1) != 0;
      float q8[8];
#pragma unroll
      for (int j = 0; j < 8; j++) {
        float a = p[2 * j], b = p[2 * j + 1];
        float keep = fb0 ? b : a, send = fb0 ? a : b;
        q8[j] = keep + __shfl_xor(send, 1, 64);
      }
      bool fb1 = (lane & 2) != 0;
      float r4[4];
#pragma unroll
      for (int j = 0; j < 4; j++) {
        float a = q8[2 * j], b = q8[2 * j + 1];
        float keep = fb1 ? b : a, send = fb1 ? a : b;
        r4[j] = keep + __shfl_xor(send, 2, 64);
      }
      bool fb2 = (lane & 4) != 0;
      float s2v[2];
#pragma unroll
      for (int j = 0; j < 2; j++) {
        float a = r4[2 * j], b = r4[2 * j + 1];
        float keep = fb2 ? b : a, send = fb2 ? a : b;
        s2v[j] = keep + __shfl_xor(send, 4, 64);
      }
      bool fb3 = (lane & 8) != 0;
      float w;
      {
        float a = s2v[0], b = s2v[1];
        float keep = fb3 ? b : a, send = fb3 ? a : b;
        w = keep + __shfl_xor(send, 8, 64);
      }
      w += __shfl_xor(w, 16, 64);
      w += __shfl_xor(w, 32, 64);
      // every lane l holds the sum for edge (l>>2)&3, head l&3
      float cA = (lane & 4) ? cf[1] : cf[0];
      float cB = (lane & 4) ? cf[3] : cf[2];
      float cfs = (lane & 8) ? cB : cA;
      float ex = cfs * __expf(w * INV_FAN);
      if (lane < 16 && (sb + kk) < deg) zacc += ex;
      // sqrt(expw) for this lane's head hh, each edge (broadcast from lane 4k+hh)
      float sav[4];
#pragma unroll
      for (int k = 0; k < 4; k++) sav[k] = sqrtf(fmaxf(__shfl(ex, k * 4 + hh, 64), 0.f));
      // ---- v-MLP (reuses h/Hs/a0/a1 registers & LDS buffer) ----
#pragma unroll
      for (int k = 0; k < 4; k++) {
        const float4* xp = (const float4*)xc + (size_t)slot[k] * 2;
        float4 xa = xp[0], xb = xp[1];
        float acc = xa.x * w1v[lane]       + xa.y * w1v[64 + lane]
                  + xa.z * w1v[128 + lane] + xa.w * w1v[192 + lane]
                  + xb.x * w1v[256 + lane] + xb.y * w1v[320 + lane]
                  + xb.z * w1v[384 + lane] + xb.w * w1v[448 + lane];
        h[k] = gelu_tanh(acc * INV_SQ8 + b1v[lane]);
      }
#pragma unroll
      for (int k = 0; k < 4; k++) Hs[wave][k][lane] = h[k];  // in-wave ordering: prior reads done
#pragma unroll
      for (int k = 0; k < 4; k++) { a0[k] = 0.f; a1[k] = 0.f; }
#pragma unroll
      for (int q = 0; q < 16; q++) {
        float4 wA = *(const float4*)&wqv[q][lane][0];
        float4 wB = *(const float4*)&wqv[q][lane + 64][0];
#pragma unroll
        for (int k = 0; k < 4; k++) {
          float4 hq = *(const float4*)&Hs[wave][k][q * 4];
          a0[k] += hq.x * wA.x + hq.y * wA.y + hq.z * wA.z + hq.w * wA.w;
          a1[k] += hq.x * wB.x + hq.y * wB.y + hq.z * wB.z + hq.w * wB.w;
        }
      }
      // ---- accumulate sqrt(expw) * v-terms ----
#pragma unroll
      for (int k = 0; k < 4; k++) {
        if (!val[k]) continue;
        float ys = ya[k].x, yv0 = ya[k].y, yv1 = ya[k].z, yv2 = ya[k].w;
        float wj0 = a0[k] * INV_HID, wj1 = a1[k] * INV_HID;
        float sav_k = sav[k];
        if (!hi) {  // v0 -> s-ch v ; vv0 -> v-ch (u=v, d)
          accS += wj0 * s0[k] * ys * sav_k;
          float b = wj1 * s0[k] * sav_k;
          acc0 += b * yv0; acc1 += b * yv1; acc2 += b * yv2;
        } else {    // v1 -> s-ch 32+v ; vv1 -> v-ch (u=32+v, d)
          float dotv = s0[k] * yv0 + s1[k] * yv1 + s2[k] * yv2;
          accS += wj0 * dotv * INV3 * sav_k;
          float c = wj1 * ys * sav_k;
          acc0 += c * s0[k]; acc1 += c * s1[k]; acc2 += c * s2[k];
        }
      }
    }
  }
  // z reduce: lanes 0..15 hold partial z for (kk, h2=lane&3); sum over kk
  float zr = zacc;
  zr += __shfl_xor(zr, 4, 64);
  zr += __shfl_xor(zr, 8, 64);
  float zf = __shfl(zr, hh, 64);  // z for this lane's channel head
  zf = (zf == 0.f) ? 1.f : zf;
  float invsz = 1.0f / sqrtf(zf);
  accS *= invsz; acc0 *= invsz; acc1 *= invsz; acc2 *= invsz;
  // wave-private aggregation + fused output linear (weights from L2)
  {
    int us = hi ? 32 + v : v;
    aggv[wave][us]       = accS;
    aggv[wave][64 + us]  = acc0;
    aggv[wave][128 + us] = acc1;
    aggv[wave][192 + us] = acc2;
    const float* agg = aggv[wave];   // in-wave DS ordering: writes precede reads
#pragma unroll
    for (int rep = 0; rep < 2; ++rep) {
      int o = lane + rep * 64;
      float acc = 0.f;
      if (o < 32) {            // out_s[w=o] = invL * sum_u s_u * Wls[u][o]
#pragma unroll
        for (int u = 0; u < 64; u++) acc += agg[u] * Wls[u * 32 + o];
      } else {                 // out_v[w][d], i = w*3+d
        int i = o - 32, w2 = i / 3, d = i - 3 * w2;
        const float* av = &agg[64 + d * 64];
#pragma unroll
        for (int u = 0; u < 64; u++) acc += av[u] * Wlv[u * 32 + w2];
      }
      out[(size_t)n * 128 + o] = acc * INV_L;
    }
  }
}

// ---------------- host launcher ----------------
extern "C" void kernel_launch(void* const* d_in, const int* in_sizes, int n_in,
                              void* d_out, int out_size, void* d_ws, size_t ws_size,
                              hipStream_t stream) {
  const int*   esrc   = (const int*)d_in[0];
  const int*   edst   = (const int*)d_in[1];
  const float* xattr  = (const float*)d_in[2];
  const float* eattr  = (const float*)d_in[3];
  const float* cutoff = (const float*)d_in[4];
  const float* node_f = (const float*)d_in[5];
  const float* wk1    = (const float*)d_in[6];
  const float* bk1    = (const float*)d_in[7];
  const float* wk2    = (const float*)d_in[8];
  const float* wv1    = (const float*)d_in[9];
  const float* bv1    = (const float*)d_in[10];
  const float* wv2    = (const float*)d_in[11];
  const float* Wdot   = (const float*)d_in[12];
  const float* Wls    = (const float*)d_in[13];
  const float* Wlv    = (const float*)d_in[14];
  float* out = (float*)d_out;

  int E = in_sizes[0];
  int N = in_sizes[5] / 128;

  // workspace layout (~61 MB):
  float* A    = (float*)d_ws;                 // N*1024 f32
  float* xc   = A + (size_t)N * 1024;         // E*8 f32 (CSR-ordered xattr)
  float* ec   = xc + (size_t)E * 8;           // E*4 f32 (CSR-ordered eattr)
  float* cc   = ec + (size_t)E * 4;           // E f32   (CSR-ordered cutoff)
  int* srcc   = (int*)(cc + (size_t)E);       // E       (CSR-ordered esrc)
  int* counts = srcc + E;                     // N   (zeroed)
  int* cursor = counts + N;                   // N   (zeroed)
  int* dbin   = cursor + N;                   // 128 (zeroed)
  int* dcur   = dbin + 128;                   // 128 (zeroed)
  int* rowptr = dcur + 128;                   // N+1
  int* doff   = rowptr + (N + 1);             // 128
  int* nperm  = doff + 128;                   // N
  int* csr    = nperm + N;                    // E

  k_zero<<<(2 * N + 256 + 255) / 256, 256, 0, stream>>>(counts, 2 * N + 256);
  k_hist<<<(E + 255) / 256, 256, 0, stream>>>(edst, counts, E);
  k_scan<<<1, 256, 0, stream>>>(counts, rowptr, N);
  k_fill<<<(E + 255) / 256, 256, 0, stream>>>(edst, rowptr, cursor, csr, E);
  k_dhist<<<(N + 255) / 256, 256, 0, stream>>>(rowptr, dbin, N);
  k_dscan<<<1, 64, 0, stream>>>(dbin, doff);
  k_dfill<<<(N + 255) / 256, 256, 0, stream>>>(rowptr, doff, dcur, nperm, N);
  k_gather<<<(E + 255) / 256, 256, 0, stream>>>(csr, esrc, xattr, eattr, cutoff,
                                                xc, ec, cc, srcc, E);
  k_nodeA<<<(N + 31) / 32, 256, 0, stream>>>(node_f, Wdot, A, N);
  int nb = (N + 3) / 4;  // one node per wave
  k_fused<<<nb, 256, 0, stream>>>(rowptr, nperm, srcc, xc, ec, cc, node_f,
                                  wk1, bk1, wk2, wv1, bv1, wv2, Wls, Wlv,
                                  A, out, N);
}

// Round 8
// 1030.842 us; speedup vs baseline: 1.1474x; 1.1474x over previous
//
#include <hip/hip_runtime.h>

// Equivariant graph attention (Transformer_41480794145180) — fp32 throughout.
//
// Pipeline (all on `stream`):
//   k_zero/k_hist/k_scan/k_fill : build CSR of edges grouped by dst node
//   k_dhist/k_dscan/k_dfill     : counting-sort nodes by degree (descending)
//   k_gather: permute eattr/cutoff/esrc into CSR slot order
//   k_nodeA : per-node A fragments (lane-contiguous layout)
//   k_mlp   : edge-parallel dense MLP (8->64->128) -> wm[slot][128], the ONLY
//             place MLP FLOPs run; output pre-scaled by INV_HID, stored so a
//             node-kernel lane reads its (wj0,wj1) as one float2
//   k_att   : wave-per-node (degree-sorted): logits from wm -> folded reduce
//             -> expw -> z (regs) -> sa (CSR order).  NO MLP, tiny LDS.
//   k_mlp   : again with V weights, overwriting wm (buffer reuse, ws ~220MB)
//   k_agg   : wave-per-node: v-terms from wm * sa -> wave agg -> fused
//             output linear -> out
//
// R8 (R7 post-mortem: interleaved fusion spilled [VGPR 256, WRITE 163MB];
// R6 diagnosis: ~715 instr/edge at 41% duty, 2 waves/SIMD — per-edge MLP
// instruction count is the cost center):
//  - MLPs depend only on edge_scalar_attr => hoisted to a dense streaming
//    edge-parallel kernel (high occupancy, write-bound ~164MB). Node kernels
//    drop to ~60-75 instr/edge, LDS 8KB/4KB, VGPR ~140 => occupancy unlocked.
//  - wm layout: per edge 128 f32 as [lo: (row0[v],row2[v]) pairs v=0..31 |
//    hi: (row1[v],row3[v]) pairs] — lane reads ONE coalesced float2.
//  - WS RISK: needs ~220MB workspace (wm = E*128 f32 reused for K then V).

constexpr float INV3    = 0.57735026918962576f;  // 1/sqrt(3)
constexpr float INV_SQ8 = 0.35355339059327373f;  // 1/sqrt(N_BASIS=8)
constexpr float INV_HID = 0.125f;                // 1/sqrt(HID=64)
constexpr float INV_FAN = 0.015625f;             // 1/sqrt(4*32*32)
constexpr float INV_L   = 0.125f;                // 1/sqrt(2*MUL=64)
constexpr int   MAXD    = 128;                   // max in-degree (Poisson(32))

// jax.nn.gelu default (approximate=True, tanh form)
__device__ __forceinline__ float gelu_tanh(float x) {
  float u = 0.7978845608028654f * (x + 0.044715f * x * x * x);
  float e = __expf(2.0f * u);            // e=inf / e=0 limits are exact
  return x * (1.0f - 1.0f / (e + 1.0f)); // = 0.5x(1+tanh(u))
}

// ---------------- CSR build ----------------
__global__ void k_zero(int* __restrict__ p, int n) {
  int i = blockIdx.x * 256 + threadIdx.x;
  if (i < n) p[i] = 0;
}

__global__ void k_hist(const int* __restrict__ dst, int* __restrict__ cnt, int E) {
  int e = blockIdx.x * 256 + threadIdx.x;
  if (e < E) atomicAdd(&cnt[dst[e]], 1);
}

// single-block exclusive scan over N counts -> rowptr[0..N]
__global__ __launch_bounds__(256) void k_scan(const int* __restrict__ cnt,
                                              int* __restrict__ rowptr, int N) {
  __shared__ int wsum[4];
  __shared__ int woff[4];
  __shared__ int carry;
  int t = threadIdx.x, wave = t >> 6, lane = t & 63;
  if (t == 0) { carry = 0; rowptr[0] = 0; }
  __syncthreads();
  for (int base = 0; base < N; base += 256) {
    int i = base + t;
    int inc = (i < N) ? cnt[i] : 0;
#pragma unroll
    for (int off = 1; off < 64; off <<= 1) {
      int y = __shfl_up(inc, off, 64);
      if (lane >= off) inc += y;
    }
    if (lane == 63) wsum[wave] = inc;
    __syncthreads();
    if (t == 0) {
      int r = 0;
      for (int w = 0; w < 4; w++) { woff[w] = r; r += wsum[w]; }
    }
    __syncthreads();
    int incl = inc + woff[wave] + carry;
    if (i < N) rowptr[i + 1] = incl;
    __syncthreads();
    if (t == 255) carry = incl;  // padded lanes add 0, so this is the chunk total
    __syncthreads();
  }
}

__global__ void k_fill(const int* __restrict__ dst, const int* __restrict__ rowptr,
                       int* __restrict__ cursor, int* __restrict__ csr, int E) {
  int e = blockIdx.x * 256 + threadIdx.x;
  if (e < E) {
    int d = dst[e];
    int s = atomicAdd(&cursor[d], 1);
    csr[rowptr[d] + s] = e;
  }
}

// ---------------- degree counting sort (descending) ----------------
__global__ void k_dhist(const int* __restrict__ rowptr, int* __restrict__ dbin, int N) {
  int n = blockIdx.x * 256 + threadIdx.x;
  if (n < N) {
    int deg = rowptr[n + 1] - rowptr[n];
    atomicAdd(&dbin[min(deg, 127)], 1);
  }
}

__global__ void k_dscan(const int* __restrict__ dbin, int* __restrict__ doff) {
  if (threadIdx.x == 0 && blockIdx.x == 0) {
    int r = 0;
    for (int d = 127; d >= 0; --d) { doff[d] = r; r += dbin[d]; }
  }
}

__global__ void k_dfill(const int* __restrict__ rowptr, const int* __restrict__ doff,
                        int* __restrict__ dcur, int* __restrict__ nperm, int N) {
  int n = blockIdx.x * 256 + threadIdx.x;
  if (n < N) {
    int d = min(rowptr[n + 1] - rowptr[n], 127);
    int p = doff[d] + atomicAdd(&dcur[d], 1);
    nperm[p] = n;
  }
}

// permute edge arrays into CSR slot order (coalesced writes, random reads)
__global__ __launch_bounds__(256) void k_gather(
    const int* __restrict__ csr, const int* __restrict__ esrc,
    const float* __restrict__ eattr, const float* __restrict__ cutoff,
    float* __restrict__ ec, float* __restrict__ cc,
    int* __restrict__ srcc, int E) {
  int p = blockIdx.x * 256 + threadIdx.x;
  if (p >= E) return;
  int e = csr[p];
  srcc[p] = esrc[e];
  cc[p] = cutoff[e];
  ((float4*)ec)[p] = ((const float4*)eattr)[e];
}

// ---------------- per-node A precompute ----------------
// A layout per node (1024 f32), lane-contiguous:
//   A0[32][4] (v,h) | A1[32][4] | A2[32][4][3] (v,h,d) | A3[32][4][3]
__global__ __launch_bounds__(256) void k_nodeA(const float* __restrict__ node_f,
                                               const float* __restrict__ Wdot,
                                               float* __restrict__ A, int N) {
  __shared__ float Wd[16384];     // 64 KiB: W_dot[4][4][32][32]
  __shared__ float nfs[32 * 128]; // 16 KiB: 32 nodes' features
  int t = threadIdx.x;
  for (int i = t; i < 16384; i += 256) Wd[i] = Wdot[i];
  int n0 = blockIdx.x * 32;
  int nEnd = min(32, N - n0);
  for (int i = t; i < nEnd * 128; i += 256) nfs[i] = node_f[n0 * 128 + i];
  __syncthreads();
  for (int nn = 0; nn < nEnd; ++nn) {
    const float* nf = &nfs[nn * 128];
    float* An = &A[(n0 + nn) * 1024];
#pragma unroll
    for (int k = 0; k < 4; k++) {
      int o = t + k * 256;  // branch below is uniform per k (no divergence)
      float acc = 0.f;
      int idx;
      if (o < 256) {        // A0 / A1 : scalar q
        int term = o >> 7, h = (o >> 5) & 3, v = o & 31;
        const float* W = &Wd[term * 4096 + h * 1024 + v];
#pragma unroll
        for (int u = 0; u < 32; u++) acc += W[u * 32] * nf[u];
        idx = term * 128 + v * 4 + h;
      } else {              // A2 / A3 : vector q
        int r = o - 256;
        int term = r / 384;                 // 0,1 -> A2,A3
        int rr = r % 384;
        int h = rr / 96, q = rr % 96, v = q / 3, d = q - 3 * (q / 3);
        const float* W = &Wd[(term + 2) * 4096 + h * 1024 + v];
#pragma unroll
        for (int u = 0; u < 32; u++) acc += W[u * 32] * nf[32 + u * 3 + d];
        idx = 256 + term * 384 + v * 12 + h * 3 + d;
      }
      An[idx] = acc;
    }
  }
}

// ---------------- edge-parallel MLP precompute ----------------
// wm[slot][128] layout: [lo half: (row0[v],row2[v]) pairs, v=0..31]
//                       [hi half: (row1[v],row3[v]) pairs, v=0..31]
// (lane j<32 outputs (out[j], out[64+j]) = rows 0,2 at v=j — adjacent pair;
//  lane j>=32 outputs rows 1,3 at v=j-32.)  Pre-scaled by INV_HID.
__global__ __launch_bounds__(256) void k_mlp(
    const int* __restrict__ csr,
    const float* __restrict__ xattr,   // E x 8 (original edge order)
    const float* __restrict__ w1, const float* __restrict__ b1,
    const float* __restrict__ w2,
    float* __restrict__ wm,            // E x 128, CSR slot order
    int E, int chunk)
{
  __shared__ __align__(16) float w1s[512];
  __shared__ float b1s[64];
  __shared__ __align__(16) float wq[16][128][4];  // wq[l/4][j][l%4] = w2[l][j]
  __shared__ __align__(16) float Hs[4][4][64];    // wave-private

  int t = threadIdx.x;
  int wave = t >> 6, lane = t & 63;
  for (int i = t; i < 512; i += 256) w1s[i] = w1[i];
  if (t < 64) b1s[t] = b1[t];
  for (int i = t; i < 8192; i += 256) { int l = i >> 7, j = i & 127; wq[l >> 2][j][l & 3] = w2[i]; }
  __syncthreads();

  int base = blockIdx.x * chunk;
  int end = min(base + chunk, E);
  int v = lane & 31;
  bool hi = lane >= 32;

  for (int sb = base + wave * 4; sb < end; sb += 16) {
    int sl[4], e[4];
#pragma unroll
    for (int k = 0; k < 4; k++) {
      sl[k] = min(sb + k, E - 1);
      e[k] = csr[sl[k]];
    }
    float h[4];
#pragma unroll
    for (int k = 0; k < 4; k++) {
      const float4* xp = (const float4*)xattr + (size_t)e[k] * 2;
      float4 xa = xp[0], xb = xp[1];
      float acc = xa.x * w1s[lane]       + xa.y * w1s[64 + lane]
                + xa.z * w1s[128 + lane] + xa.w * w1s[192 + lane]
                + xb.x * w1s[256 + lane] + xb.y * w1s[320 + lane]
                + xb.z * w1s[384 + lane] + xb.w * w1s[448 + lane];
      h[k] = gelu_tanh(acc * INV_SQ8 + b1s[lane]);
    }
#pragma unroll
    for (int k = 0; k < 4; k++) Hs[wave][k][lane] = h[k];  // wave-private
    float a0[4] = {0, 0, 0, 0}, a1[4] = {0, 0, 0, 0};
#pragma unroll
    for (int q = 0; q < 16; q++) {
      float4 wA = *(const float4*)&wq[q][lane][0];
      float4 wB = *(const float4*)&wq[q][lane + 64][0];
#pragma unroll
      for (int k = 0; k < 4; k++) {
        float4 hq = *(const float4*)&Hs[wave][k][q * 4];
        a0[k] += hq.x * wA.x + hq.y * wA.y + hq.z * wA.z + hq.w * wA.w;
        a1[k] += hq.x * wB.x + hq.y * wB.y + hq.z * wB.z + hq.w * wB.w;
      }
    }
#pragma unroll
    for (int k = 0; k < 4; k++) {
      if (sb + k < end) {
        float2 o = make_float2(a0[k] * INV_HID, a1[k] * INV_HID);
        ((float2*)wm)[(size_t)sl[k] * 64 + (hi ? 32 : 0) + v] = o;
      }
    }
  }
}

// ---------------- attention pass (wave-per-node, degree-sorted) ----------------
__global__ __launch_bounds__(256) void k_att(
    const int* __restrict__ rowptr,
    const int* __restrict__ nperm,     // degree-sorted node ids
    const int* __restrict__ srcc,      // E, CSR order
    const float* __restrict__ ec,      // E x 4, CSR order
    const float* __restrict__ cc,      // E, CSR order
    const float* __restrict__ node_f,  // N x 128
    const float* __restrict__ wm,      // E x 128 (K-MLP, INV_HID folded)
    const float* __restrict__ A,       // N x 1024 (lane-contiguous layout)
    float* __restrict__ sa_out,        // E x 4, CSR slot order
    int N)
{
  __shared__ float expws[4][MAXD][4];  // per-wave

  int t = threadIdx.x;
  int wave = t >> 6, lane = t & 63;
  int idx = blockIdx.x * 4 + wave;
  if (idx >= N) return;
  int n = nperm[idx];
  int row0 = rowptr[n];
  int deg = min(rowptr[n + 1] - row0, MAXD);
  if (deg <= 0) return;

  int v = lane & 31;
  bool hi = lane >= 32;
  int kk = (lane >> 2) & 3;

  // A fragments in registers
  float aS[4], aV[12];
  {
    const float* Ab = A + (size_t)n * 1024;
    const float* ps = Ab + (hi ? 128 : 0) + v * 4;
    float4 t0 = *(const float4*)ps;
    aS[0] = t0.x; aS[1] = t0.y; aS[2] = t0.z; aS[3] = t0.w;
    const float* pv = Ab + (hi ? 640 : 256) + v * 12;
    float4 u0 = *(const float4*)pv;
    float4 u1 = *(const float4*)(pv + 4);
    float4 u2 = *(const float4*)(pv + 8);
    aV[0] = u0.x; aV[1] = u0.y; aV[2]  = u0.z; aV[3]  = u0.w;
    aV[4] = u1.x; aV[5] = u1.y; aV[6]  = u1.z; aV[7]  = u1.w;
    aV[8] = u2.x; aV[9] = u2.y; aV[10] = u2.z; aV[11] = u2.w;
  }

  int iters = (deg + 3) >> 2;
  float zacc = 0.f;  // lanes 0..15: partial z for (kk, h2=lane&3)

  for (int it = 0; it < iters; ++it) {
    int sb = it * 4;
    int slot[4]; int sp[4];
#pragma unroll
    for (int k = 0; k < 4; k++) slot[k] = row0 + min(sb + k, deg - 1);
#pragma unroll
    for (int k = 0; k < 4; k++) sp[k] = srcc[slot[k]];
    float4 ya[4]; float cf[4]; float2 wj[4]; float s0[4], s1[4], s2[4];
#pragma unroll
    for (int k = 0; k < 4; k++) {
      ya[k] = ((const float4*)ec)[slot[k]];
      cf[k] = (sb + k < deg) ? cc[slot[k]] : 0.f;   // OOB -> expw 0
      wj[k] = ((const float2*)wm)[(size_t)slot[k] * 64 + (hi ? 32 : 0) + v];
      const float* nf = &node_f[(size_t)sp[k] * 128];
      if (!hi) { s0[k] = nf[v]; s1[k] = 0.f; s2[k] = 0.f; }
      else     { s0[k] = nf[32 + v * 3]; s1[k] = nf[33 + v * 3]; s2[k] = nf[34 + v * 3]; }
    }
    // attention logits; p[m], m = k*4 + h2
    float p[16];
#pragma unroll
    for (int k = 0; k < 4; k++) {
      float ys = ya[k].x, yv0 = ya[k].y, yv1 = ya[k].z, yv2 = ya[k].w;
      if (!hi) {  // lanes 0..31: k0 (row 0) + kv0 (row 2)
        float k0 = wj[k].x * s0[k] * ys;
        float kb = INV3 * wj[k].y * s0[k];
#pragma unroll
        for (int h2 = 0; h2 < 4; h2++)
          p[k * 4 + h2] = aS[h2] * k0 +
              kb * (aV[h2 * 3] * yv0 + aV[h2 * 3 + 1] * yv1 + aV[h2 * 3 + 2] * yv2);
      } else {    // lanes 32..63: k1 (row 1) + kv1 (row 3)
        float dotv = s0[k] * yv0 + s1[k] * yv1 + s2[k] * yv2;
        float k1 = wj[k].x * dotv * INV3;
        float kc = INV3 * wj[k].y * ys;
#pragma unroll
        for (int h2 = 0; h2 < 4; h2++)
          p[k * 4 + h2] = aS[h2] * k1 +
              kc * (aV[h2 * 3] * s0[k] + aV[h2 * 3 + 1] * s1[k] + aV[h2 * 3 + 2] * s2[k]);
      }
    }
    // folded butterfly: 16 per-lane values -> full sums keyed by lane&15
    bool fb0 = (lane & 1) != 0;
    float q8[8];
#pragma unroll
    for (int j = 0; j < 8; j++) {
      float a = p[2 * j], b = p[2 * j + 1];
      float keep = fb0 ? b : a, send = fb0 ? a : b;
      q8[j] = keep + __shfl_xor(send, 1, 64);
    }
    bool fb1 = (lane & 2) != 0;
    float r4[4];
#pragma unroll
    for (int j = 0; j < 4; j++) {
      float a = q8[2 * j], b = q8[2 * j + 1];
      float keep = fb1 ? b : a, send = fb1 ? a : b;
      r4[j] = keep + __shfl_xor(send, 2, 64);
    }
    bool fb2 = (lane & 4) != 0;
    float s2v[2];
#pragma unroll
    for (int j = 0; j < 2; j++) {
      float a = r4[2 * j], b = r4[2 * j + 1];
      float keep = fb2 ? b : a, send = fb2 ? a : b;
      s2v[j] = keep + __shfl_xor(send, 4, 64);
    }
    bool fb3 = (lane & 8) != 0;
    float w;
    {
      float a = s2v[0], b = s2v[1];
      float keep = fb3 ? b : a, send = fb3 ? a : b;
      w = keep + __shfl_xor(send, 8, 64);
    }
    w += __shfl_xor(w, 16, 64);
    w += __shfl_xor(w, 32, 64);
    // lane l holds sum for edge (l>>2)&3, head l&3
    float cA = (lane & 4) ? cf[1] : cf[0];
    float cB = (lane & 4) ? cf[3] : cf[2];
    float cfs = (lane & 8) ? cB : cA;
    int slotw = sb + kk;
    float ex = cfs * __expf(w * INV_FAN);
    if (lane < 16 && slotw < deg) {
      expws[wave][slotw][lane & 3] = ex;
      zacc += ex;
    }
  }
  // z reduce: lanes 0..15 hold partials (kk, h2=lane&3); sum over kk
  float zr = zacc;
  zr += __shfl_xor(zr, 4, 64);
  zr += __shfl_xor(zr, 8, 64);
  float zf = __shfl(zr, lane & 3, 64);
  zf = (zf == 0.f) ? 1.f : zf;
  for (int i = lane; i < deg * 4; i += 64) {
    int slot = i >> 2;  // i&3 == lane&3
    float alpha = expws[wave][slot][lane & 3] / zf;
    sa_out[(size_t)(row0 + slot) * 4 + (lane & 3)] = sqrtf(fmaxf(alpha, 0.f));
  }
}

// ---------------- aggregation pass + output linear ----------------
__global__ __launch_bounds__(256) void k_agg(
    const int* __restrict__ rowptr,
    const int* __restrict__ nperm,
    const int* __restrict__ srcc,
    const float* __restrict__ ec,
    const float* __restrict__ node_f,
    const float* __restrict__ wm,      // E x 128 (V-MLP, INV_HID folded)
    const float* __restrict__ Wls, const float* __restrict__ Wlv,  // 64x32 each
    const float* __restrict__ sa_in,   // E x 4, CSR slot order
    float* __restrict__ out,           // N x 128
    int N)
{
  __shared__ float aggv[4][256];  // [wave][ch']: ch'=u (s) | 64+d*64+u (v)

  int t = threadIdx.x;
  int wave = t >> 6, lane = t & 63;
  int idx = blockIdx.x * 4 + wave;
  if (idx >= N) return;
  int n = nperm[idx];
  int row0 = rowptr[n];
  int deg = min(rowptr[n + 1] - row0, MAXD);

  int v = lane & 31;
  bool hi = lane >= 32;
  int hh = v >> 3;  // head of channel v (m = MUL/H = 8)
  float accS = 0.f, acc0 = 0.f, acc1 = 0.f, acc2 = 0.f;

  if (deg > 0) {
    int iters = (deg + 3) >> 2;
    for (int it = 0; it < iters; ++it) {
      int sb = it * 4;
      int slot[4]; int sp[4];
#pragma unroll
      for (int k = 0; k < 4; k++) slot[k] = row0 + min(sb + k, deg - 1);
#pragma unroll
      for (int k = 0; k < 4; k++) sp[k] = srcc[slot[k]];
      float4 ya[4]; float sav[4]; float2 wj[4]; float s0[4], s1[4], s2[4];
#pragma unroll
      for (int k = 0; k < 4; k++) {
        sav[k] = (sb + k < deg) ? sa_in[(size_t)slot[k] * 4 + hh] : 0.f;  // OOB -> 0
        ya[k] = ((const float4*)ec)[slot[k]];
        wj[k] = ((const float2*)wm)[(size_t)slot[k] * 64 + (hi ? 32 : 0) + v];
        const float* nf = &node_f[(size_t)sp[k] * 128];
        if (!hi) { s0[k] = nf[v]; s1[k] = 0.f; s2[k] = 0.f; }
        else     { s0[k] = nf[32 + v * 3]; s1[k] = nf[33 + v * 3]; s2[k] = nf[34 + v * 3]; }
      }
#pragma unroll
      for (int k = 0; k < 4; k++) {
        float ys = ya[k].x, yv0 = ya[k].y, yv1 = ya[k].z, yv2 = ya[k].w;
        float sav_k = sav[k];
        if (!hi) {  // v0 -> s-ch v ; vv0 -> v-ch (u=v, d)
          accS += wj[k].x * s0[k] * ys * sav_k;
          float b = wj[k].y * s0[k] * sav_k;
          acc0 += b * yv0; acc1 += b * yv1; acc2 += b * yv2;
        } else {    // v1 -> s-ch 32+v ; vv1 -> v-ch (u=32+v, d)
          float dotv = s0[k] * yv0 + s1[k] * yv1 + s2[k] * yv2;
          accS += wj[k].x * dotv * INV3 * sav_k;
          float c = wj[k].y * ys * sav_k;
          acc0 += c * s0[k]; acc1 += c * s1[k]; acc2 += c * s2[k];
        }
      }
    }
  }
  // wave-private aggregation + fused output linear (weights from L2)
  {
    int us = hi ? 32 + v : v;
    aggv[wave][us]       = accS;
    aggv[wave][64 + us]  = acc0;
    aggv[wave][128 + us] = acc1;
    aggv[wave][192 + us] = acc2;
    const float* agg = aggv[wave];   // in-wave DS ordering: writes precede reads
#pragma unroll
    for (int rep = 0; rep < 2; ++rep) {
      int o = lane + rep * 64;
      float acc = 0.f;
      if (o < 32) {
#pragma unroll
        for (int u = 0; u < 64; u++) acc += agg[u] * Wls[u * 32 + o];
      } else {
        int i = o - 32, w2 = i / 3, d = i - 3 * w2;
        const float* av = &agg[64 + d * 64];
#pragma unroll
        for (int u = 0; u < 64; u++) acc += av[u] * Wlv[u * 32 + w2];
      }
      out[(size_t)n * 128 + o] = acc * INV_L;
    }
  }
}

// ---------------- host launcher ----------------
extern "C" void kernel_launch(void* const* d_in, const int* in_sizes, int n_in,
                              void* d_out, int out_size, void* d_ws, size_t ws_size,
                              hipStream_t stream) {
  const int*   esrc   = (const int*)d_in[0];
  const int*   edst   = (const int*)d_in[1];
  const float* xattr  = (const float*)d_in[2];
  const float* eattr  = (const float*)d_in[3];
  const float* cutoff = (const float*)d_in[4];
  const float* node_f = (const float*)d_in[5];
  const float* wk1    = (const float*)d_in[6];
  const float* bk1    = (const float*)d_in[7];
  const float* wk2    = (const float*)d_in[8];
  const float* wv1    = (const float*)d_in[9];
  const float* bv1    = (const float*)d_in[10];
  const float* wv2    = (const float*)d_in[11];
  const float* Wdot   = (const float*)d_in[12];
  const float* Wls    = (const float*)d_in[13];
  const float* Wlv    = (const float*)d_in[14];
  float* out = (float*)d_out;

  int E = in_sizes[0];
  int N = in_sizes[5] / 128;

  // workspace layout (~220 MB; wm reused for K-MLP then V-MLP):
  float* A    = (float*)d_ws;                 // N*1024 f32
  float* sa   = A + (size_t)N * 1024;         // E*4 f32
  float* ec   = sa + (size_t)E * 4;           // E*4 f32 (CSR-ordered eattr)
  float* cc   = ec + (size_t)E * 4;           // E f32   (CSR-ordered cutoff)
  int* srcc   = (int*)(cc + (size_t)E);       // E       (CSR-ordered esrc)
  int* counts = srcc + E;                     // N   (zeroed)
  int* cursor = counts + N;                   // N   (zeroed)
  int* dbin   = cursor + N;                   // 128 (zeroed)
  int* dcur   = dbin + 128;                   // 128 (zeroed)
  int* rowptr = dcur + 128;                   // N+1
  int* doff   = rowptr + (N + 1);             // 128
  int* nperm  = doff + 128;                   // N
  int* csr    = nperm + N;                    // E
  float* wm   = (float*)(csr + E);            // E*128 f32 (163.8 MB)

  k_zero<<<(2 * N + 256 + 255) / 256, 256, 0, stream>>>(counts, 2 * N + 256);
  k_hist<<<(E + 255) / 256, 256, 0, stream>>>(edst, counts, E);
  k_scan<<<1, 256, 0, stream>>>(counts, rowptr, N);
  k_fill<<<(E + 255) / 256, 256, 0, stream>>>(edst, rowptr, cursor, csr, E);
  k_dhist<<<(N + 255) / 256, 256, 0, stream>>>(rowptr, dbin, N);
  k_dscan<<<1, 64, 0, stream>>>(dbin, doff);
  k_dfill<<<(N + 255) / 256, 256, 0, stream>>>(rowptr, doff, dcur, nperm, N);
  k_gather<<<(E + 255) / 256, 256, 0, stream>>>(csr, esrc, eattr, cutoff,
                                                ec, cc, srcc, E);
  k_nodeA<<<(N + 31) / 32, 256, 0, stream>>>(node_f, Wdot, A, N);

  int chunk = ((E + 2047) / 2048 + 15) & ~15;   // slots per k_mlp block
  int mgrid = (E + chunk - 1) / chunk;
  int nb = (N + 3) / 4;                         // one node per wave

  k_mlp<<<mgrid, 256, 0, stream>>>(csr, xattr, wk1, bk1, wk2, wm, E, chunk);
  k_att<<<nb, 256, 0, stream>>>(rowptr, nperm, srcc, ec, cc, node_f, wm, A, sa, N);
  k_mlp<<<mgrid, 256, 0, stream>>>(csr, xattr, wv1, bv1, wv2, wm, E, chunk);
  k_agg<<<nb, 256, 0, stream>>>(rowptr, nperm, srcc, ec, node_f, wm,
                                Wls, Wlv, sa, out, N);
}

// Round 9
// 952.334 us; speedup vs baseline: 1.2420x; 1.0824x over previous
//
#include <hip/hip_runtime.h>

// Equivariant graph attention (Transformer_41480794145180) — fp32 throughout.
//
// Pipeline (all on `stream`):
//   k_zero/k_hist/k_scan/k_fill : build CSR of edges grouped by dst node
//   k_dhist/k_dscan/k_dfill     : counting-sort nodes by degree (descending)
//   k_gather: permute xattr/eattr/cutoff/esrc into CSR slot order
//   k_nodeA : per-node A fragments (lane-contiguous layout)
//   k_mlp   : edge-parallel dense MLP (8->64->128) -> wm[slot][128];
//             INPUT READ LINEARLY from xc (CSR order) — no indirection
//   k_att   : wave-per-node (degree-sorted): logits from wm -> folded reduce
//             -> expw -> z (regs) -> sa (CSR order)
//   k_mlp   : again with V weights, overwriting wm (buffer reuse)
//   k_agg   : wave-per-node: v-terms from wm * sa -> wave agg -> fused
//             output linear -> out
//
// R9 (R8 post-mortem: k_mlp x2 = 664us is 64% of total; VALU 35%, occ 12%,
// FETCH 20MB => latency-bound on the csr->xattr 2-hop random gather consumed
// immediately by the hidden layer; compute floor ~18us, write floor ~29us):
//  - xc restored: k_gather permutes xattr to CSR order once; k_mlp reads it
//    LINEARLY by slot (no csr load, sequential 32B/edge).
//  - k_mlp chunk 160 -> 512 slots (625 blocks, all-resident, weight staging
//    amortized 3.2x).

constexpr float INV3    = 0.57735026918962576f;  // 1/sqrt(3)
constexpr float INV_SQ8 = 0.35355339059327373f;  // 1/sqrt(N_BASIS=8)
constexpr float INV_HID = 0.125f;                // 1/sqrt(HID=64)
constexpr float INV_FAN = 0.015625f;             // 1/sqrt(4*32*32)
constexpr float INV_L   = 0.125f;                // 1/sqrt(2*MUL=64)
constexpr int   MAXD    = 128;                   // max in-degree (Poisson(32))

// jax.nn.gelu default (approximate=True, tanh form)
__device__ __forceinline__ float gelu_tanh(float x) {
  float u = 0.7978845608028654f * (x + 0.044715f * x * x * x);
  float e = __expf(2.0f * u);            // e=inf / e=0 limits are exact
  return x * (1.0f - 1.0f / (e + 1.0f)); // = 0.5x(1+tanh(u))
}

// ---------------- CSR build ----------------
__global__ void k_zero(int* __restrict__ p, int n) {
  int i = blockIdx.x * 256 + threadIdx.x;
  if (i < n) p[i] = 0;
}

__global__ void k_hist(const int* __restrict__ dst, int* __restrict__ cnt, int E) {
  int e = blockIdx.x * 256 + threadIdx.x;
  if (e < E) atomicAdd(&cnt[dst[e]], 1);
}

// single-block exclusive scan over N counts -> rowptr[0..N]
__global__ __launch_bounds__(256) void k_scan(const int* __restrict__ cnt,
                                              int* __restrict__ rowptr, int N) {
  __shared__ int wsum[4];
  __shared__ int woff[4];
  __shared__ int carry;
  int t = threadIdx.x, wave = t >> 6, lane = t & 63;
  if (t == 0) { carry = 0; rowptr[0] = 0; }
  __syncthreads();
  for (int base = 0; base < N; base += 256) {
    int i = base + t;
    int inc = (i < N) ? cnt[i] : 0;
#pragma unroll
    for (int off = 1; off < 64; off <<= 1) {
      int y = __shfl_up(inc, off, 64);
      if (lane >= off) inc += y;
    }
    if (lane == 63) wsum[wave] = inc;
    __syncthreads();
    if (t == 0) {
      int r = 0;
      for (int w = 0; w < 4; w++) { woff[w] = r; r += wsum[w]; }
    }
    __syncthreads();
    int incl = inc + woff[wave] + carry;
    if (i < N) rowptr[i + 1] = incl;
    __syncthreads();
    if (t == 255) carry = incl;  // padded lanes add 0, so this is the chunk total
    __syncthreads();
  }
}

__global__ void k_fill(const int* __restrict__ dst, const int* __restrict__ rowptr,
                       int* __restrict__ cursor, int* __restrict__ csr, int E) {
  int e = blockIdx.x * 256 + threadIdx.x;
  if (e < E) {
    int d = dst[e];
    int s = atomicAdd(&cursor[d], 1);
    csr[rowptr[d] + s] = e;
  }
}

// ---------------- degree counting sort (descending) ----------------
__global__ void k_dhist(const int* __restrict__ rowptr, int* __restrict__ dbin, int N) {
  int n = blockIdx.x * 256 + threadIdx.x;
  if (n < N) {
    int deg = rowptr[n + 1] - rowptr[n];
    atomicAdd(&dbin[min(deg, 127)], 1);
  }
}

__global__ void k_dscan(const int* __restrict__ dbin, int* __restrict__ doff) {
  if (threadIdx.x == 0 && blockIdx.x == 0) {
    int r = 0;
    for (int d = 127; d >= 0; --d) { doff[d] = r; r += dbin[d]; }
  }
}

__global__ void k_dfill(const int* __restrict__ rowptr, const int* __restrict__ doff,
                        int* __restrict__ dcur, int* __restrict__ nperm, int N) {
  int n = blockIdx.x * 256 + threadIdx.x;
  if (n < N) {
    int d = min(rowptr[n + 1] - rowptr[n], 127);
    int p = doff[d] + atomicAdd(&dcur[d], 1);
    nperm[p] = n;
  }
}

// permute edge arrays into CSR slot order (coalesced writes, random reads)
__global__ __launch_bounds__(256) void k_gather(
    const int* __restrict__ csr, const int* __restrict__ esrc,
    const float* __restrict__ xattr, const float* __restrict__ eattr,
    const float* __restrict__ cutoff,
    float* __restrict__ xc, float* __restrict__ ec, float* __restrict__ cc,
    int* __restrict__ srcc, int E) {
  int p = blockIdx.x * 256 + threadIdx.x;
  if (p >= E) return;
  int e = csr[p];
  srcc[p] = esrc[e];
  cc[p] = cutoff[e];
  ((float4*)ec)[p] = ((const float4*)eattr)[e];
  const float4* xs = (const float4*)xattr + (size_t)e * 2;
  float4* xd = (float4*)xc + (size_t)p * 2;
  xd[0] = xs[0]; xd[1] = xs[1];
}

// ---------------- per-node A precompute ----------------
// A layout per node (1024 f32), lane-contiguous:
//   A0[32][4] (v,h) | A1[32][4] | A2[32][4][3] (v,h,d) | A3[32][4][3]
__global__ __launch_bounds__(256) void k_nodeA(const float* __restrict__ node_f,
                                               const float* __restrict__ Wdot,
                                               float* __restrict__ A, int N) {
  __shared__ float Wd[16384];     // 64 KiB: W_dot[4][4][32][32]
  __shared__ float nfs[32 * 128]; // 16 KiB: 32 nodes' features
  int t = threadIdx.x;
  for (int i = t; i < 16384; i += 256) Wd[i] = Wdot[i];
  int n0 = blockIdx.x * 32;
  int nEnd = min(32, N - n0);
  for (int i = t; i < nEnd * 128; i += 256) nfs[i] = node_f[n0 * 128 + i];
  __syncthreads();
  for (int nn = 0; nn < nEnd; ++nn) {
    const float* nf = &nfs[nn * 128];
    float* An = &A[(n0 + nn) * 1024];
#pragma unroll
    for (int k = 0; k < 4; k++) {
      int o = t + k * 256;  // branch below is uniform per k (no divergence)
      float acc = 0.f;
      int idx;
      if (o < 256) {        // A0 / A1 : scalar q
        int term = o >> 7, h = (o >> 5) & 3, v = o & 31;
        const float* W = &Wd[term * 4096 + h * 1024 + v];
#pragma unroll
        for (int u = 0; u < 32; u++) acc += W[u * 32] * nf[u];
        idx = term * 128 + v * 4 + h;
      } else {              // A2 / A3 : vector q
        int r = o - 256;
        int term = r / 384;                 // 0,1 -> A2,A3
        int rr = r % 384;
        int h = rr / 96, q = rr % 96, v = q / 3, d = q - 3 * (q / 3);
        const float* W = &Wd[(term + 2) * 4096 + h * 1024 + v];
#pragma unroll
        for (int u = 0; u < 32; u++) acc += W[u * 32] * nf[32 + u * 3 + d];
        idx = 256 + term * 384 + v * 12 + h * 3 + d;
      }
      An[idx] = acc;
    }
  }
}

// ---------------- edge-parallel MLP precompute ----------------
// wm[slot][128] layout: [lo half: (row0[v],row2[v]) pairs, v=0..31]
//                       [hi half: (row1[v],row3[v]) pairs, v=0..31]
// Pre-scaled by INV_HID. Input xc read LINEARLY by slot (CSR order).
__global__ __launch_bounds__(256) void k_mlp(
    const float* __restrict__ xc,      // E x 8, CSR slot order
    const float* __restrict__ w1, const float* __restrict__ b1,
    const float* __restrict__ w2,
    float* __restrict__ wm,            // E x 128, CSR slot order
    int E, int chunk)
{
  __shared__ __align__(16) float w1s[512];
  __shared__ float b1s[64];
  __shared__ __align__(16) float wq[16][128][4];  // wq[l/4][j][l%4] = w2[l][j]
  __shared__ __align__(16) float Hs[4][4][64];    // wave-private

  int t = threadIdx.x;
  int wave = t >> 6, lane = t & 63;
  for (int i = t; i < 512; i += 256) w1s[i] = w1[i];
  if (t < 64) b1s[t] = b1[t];
  for (int i = t; i < 8192; i += 256) { int l = i >> 7, j = i & 127; wq[l >> 2][j][l & 3] = w2[i]; }
  __syncthreads();

  int base = blockIdx.x * chunk;
  int end = min(base + chunk, E);
  int v = lane & 31;
  bool hi = lane >= 32;

  for (int sb = base + wave * 4; sb < end; sb += 16) {
    int sl[4];
#pragma unroll
    for (int k = 0; k < 4; k++) sl[k] = min(sb + k, E - 1);
    float h[4];
#pragma unroll
    for (int k = 0; k < 4; k++) {
      const float4* xp = (const float4*)xc + (size_t)sl[k] * 2;  // linear stream
      float4 xa = xp[0], xb = xp[1];
      float acc = xa.x * w1s[lane]       + xa.y * w1s[64 + lane]
                + xa.z * w1s[128 + lane] + xa.w * w1s[192 + lane]
                + xb.x * w1s[256 + lane] + xb.y * w1s[320 + lane]
                + xb.z * w1s[384 + lane] + xb.w * w1s[448 + lane];
      h[k] = gelu_tanh(acc * INV_SQ8 + b1s[lane]);
    }
#pragma unroll
    for (int k = 0; k < 4; k++) Hs[wave][k][lane] = h[k];  // wave-private
    float a0[4] = {0, 0, 0, 0}, a1[4] = {0, 0, 0, 0};
#pragma unroll
    for (int q = 0; q < 16; q++) {
      float4 wA = *(const float4*)&wq[q][lane][0];
      float4 wB = *(const float4*)&wq[q][lane + 64][0];
#pragma unroll
      for (int k = 0; k < 4; k++) {
        float4 hq = *(const float4*)&Hs[wave][k][q * 4];
        a0[k] += hq.x * wA.x + hq.y * wA.y + hq.z * wA.z + hq.w * wA.w;
        a1[k] += hq.x * wB.x + hq.y * wB.y + hq.z * wB.z + hq.w * wB.w;
      }
    }
#pragma unroll
    for (int k = 0; k < 4; k++) {
      if (sb + k < end) {
        float2 o = make_float2(a0[k] * INV_HID, a1[k] * INV_HID);
        ((float2*)wm)[(size_t)sl[k] * 64 + (hi ? 32 : 0) + v] = o;
      }
    }
  }
}

// ---------------- attention pass (wave-per-node, degree-sorted) ----------------
__global__ __launch_bounds__(256) void k_att(
    const int* __restrict__ rowptr,
    const int* __restrict__ nperm,     // degree-sorted node ids
    const int* __restrict__ srcc,      // E, CSR order
    const float* __restrict__ ec,      // E x 4, CSR order
    const float* __restrict__ cc,      // E, CSR order
    const float* __restrict__ node_f,  // N x 128
    const float* __restrict__ wm,      // E x 128 (K-MLP, INV_HID folded)
    const float* __restrict__ A,       // N x 1024 (lane-contiguous layout)
    float* __restrict__ sa_out,        // E x 4, CSR slot order
    int N)
{
  __shared__ float expws[4][MAXD][4];  // per-wave

  int t = threadIdx.x;
  int wave = t >> 6, lane = t & 63;
  int idx = blockIdx.x * 4 + wave;
  if (idx >= N) return;
  int n = nperm[idx];
  int row0 = rowptr[n];
  int deg = min(rowptr[n + 1] - row0, MAXD);
  if (deg <= 0) return;

  int v = lane & 31;
  bool hi = lane >= 32;
  int kk = (lane >> 2) & 3;

  // A fragments in registers
  float aS[4], aV[12];
  {
    const float* Ab = A + (size_t)n * 1024;
    const float* ps = Ab + (hi ? 128 : 0) + v * 4;
    float4 t0 = *(const float4*)ps;
    aS[0] = t0.x; aS[1] = t0.y; aS[2] = t0.z; aS[3] = t0.w;
    const float* pv = Ab + (hi ? 640 : 256) + v * 12;
    float4 u0 = *(const float4*)pv;
    float4 u1 = *(const float4*)(pv + 4);
    float4 u2 = *(const float4*)(pv + 8);
    aV[0] = u0.x; aV[1] = u0.y; aV[2]  = u0.z; aV[3]  = u0.w;
    aV[4] = u1.x; aV[5] = u1.y; aV[6]  = u1.z; aV[7]  = u1.w;
    aV[8] = u2.x; aV[9] = u2.y; aV[10] = u2.z; aV[11] = u2.w;
  }

  int iters = (deg + 3) >> 2;
  float zacc = 0.f;  // lanes 0..15: partial z for (kk, h2=lane&3)

  for (int it = 0; it < iters; ++it) {
    int sb = it * 4;
    int slot[4]; int sp[4];
#pragma unroll
    for (int k = 0; k < 4; k++) slot[k] = row0 + min(sb + k, deg - 1);
#pragma unroll
    for (int k = 0; k < 4; k++) sp[k] = srcc[slot[k]];
    float4 ya[4]; float cf[4]; float2 wj[4]; float s0[4], s1[4], s2[4];
#pragma unroll
    for (int k = 0; k < 4; k++) {
      ya[k] = ((const float4*)ec)[slot[k]];
      cf[k] = (sb + k < deg) ? cc[slot[k]] : 0.f;   // OOB -> expw 0
      wj[k] = ((const float2*)wm)[(size_t)slot[k] * 64 + (hi ? 32 : 0) + v];
      const float* nf = &node_f[(size_t)sp[k] * 128];
      if (!hi) { s0[k] = nf[v]; s1[k] = 0.f; s2[k] = 0.f; }
      else     { s0[k] = nf[32 + v * 3]; s1[k] = nf[33 + v * 3]; s2[k] = nf[34 + v * 3]; }
    }
    // attention logits; p[m], m = k*4 + h2
    float p[16];
#pragma unroll
    for (int k = 0; k < 4; k++) {
      float ys = ya[k].x, yv0 = ya[k].y, yv1 = ya[k].z, yv2 = ya[k].w;
      if (!hi) {  // lanes 0..31: k0 (row 0) + kv0 (row 2)
        float k0 = wj[k].x * s0[k] * ys;
        float kb = INV3 * wj[k].y * s0[k];
#pragma unroll
        for (int h2 = 0; h2 < 4; h2++)
          p[k * 4 + h2] = aS[h2] * k0 +
              kb * (aV[h2 * 3] * yv0 + aV[h2 * 3 + 1] * yv1 + aV[h2 * 3 + 2] * yv2);
      } else {    // lanes 32..63: k1 (row 1) + kv1 (row 3)
        float dotv = s0[k] * yv0 + s1[k] * yv1 + s2[k] * yv2;
        float k1 = wj[k].x * dotv * INV3;
        float kc = INV3 * wj[k].y * ys;
#pragma unroll
        for (int h2 = 0; h2 < 4; h2++)
          p[k * 4 + h2] = aS[h2] * k1 +
              kc * (aV[h2 * 3] * s0[k] + aV[h2 * 3 + 1] * s1[k] + aV[h2 * 3 + 2] * s2[k]);
      }
    }
    // folded butterfly: 16 per-lane values -> full sums keyed by lane&15
    bool fb0 = (lane & 1) != 0;
    float q8[8];
#pragma unroll
    for (int j = 0; j < 8; j++) {
      float a = p[2 * j], b = p[2 * j + 1];
      float keep = fb0 ? b : a, send = fb0 ? a : b;
      q8[j] = keep + __shfl_xor(send, 1, 64);
    }
    bool fb1 = (lane & 2) != 0;
    float r4[4];
#pragma unroll
    for (int j = 0; j < 4; j++) {
      float a = q8[2 * j], b = q8[2 * j + 1];
      float keep = fb1 ? b : a, send = fb1 ? a : b;
      r4[j] = keep + __shfl_xor(send, 2, 64);
    }
    bool fb2 = (lane & 4) != 0;
    float s2v[2];
#pragma unroll
    for (int j = 0; j < 2; j++) {
      float a = r4[2 * j], b = r4[2 * j + 1];
      float keep = fb2 ? b : a, send = fb2 ? a : b;
      s2v[j] = keep + __shfl_xor(send, 4, 64);
    }
    bool fb3 = (lane & 8) != 0;
    float w;
    {
      float a = s2v[0], b = s2v[1];
      float keep = fb3 ? b : a, send = fb3 ? a : b;
      w = keep + __shfl_xor(send, 8, 64);
    }
    w += __shfl_xor(w, 16, 64);
    w += __shfl_xor(w, 32, 64);
    // lane l holds sum for edge (l>>2)&3, head l&3
    float cA = (lane & 4) ? cf[1] : cf[0];
    float cB = (lane & 4) ? cf[3] : cf[2];
    float cfs = (lane & 8) ? cB : cA;
    int slotw = sb + kk;
    float ex = cfs * __expf(w * INV_FAN);
    if (lane < 16 && slotw < deg) {
      expws[wave][slotw][lane & 3] = ex;
      zacc += ex;
    }
  }
  // z reduce: lanes 0..15 hold partials (kk, h2=lane&3); sum over kk
  float zr = zacc;
  zr += __shfl_xor(zr, 4, 64);
  zr += __shfl_xor(zr, 8, 64);
  float zf = __shfl(zr, lane & 3, 64);
  zf = (zf == 0.f) ? 1.f : zf;
  for (int i = lane; i < deg * 4; i += 64) {
    int slot = i >> 2;  // i&3 == lane&3
    float alpha = expws[wave][slot][lane & 3] / zf;
    sa_out[(size_t)(row0 + slot) * 4 + (lane & 3)] = sqrtf(fmaxf(alpha, 0.f));
  }
}

// ---------------- aggregation pass + output linear ----------------
__global__ __launch_bounds__(256) void k_agg(
    const int* __restrict__ rowptr,
    const int* __restrict__ nperm,
    const int* __restrict__ srcc,
    const float* __restrict__ ec,
    const float* __restrict__ node_f,
    const float* __restrict__ wm,      // E x 128 (V-MLP, INV_HID folded)
    const float* __restrict__ Wls, const float* __restrict__ Wlv,  // 64x32 each
    const float* __restrict__ sa_in,   // E x 4, CSR slot order
    float* __restrict__ out,           // N x 128
    int N)
{
  __shared__ float aggv[4][256];  // [wave][ch']: ch'=u (s) | 64+d*64+u (v)

  int t = threadIdx.x;
  int wave = t >> 6, lane = t & 63;
  int idx = blockIdx.x * 4 + wave;
  if (idx >= N) return;
  int n = nperm[idx];
  int row0 = rowptr[n];
  int deg = min(rowptr[n + 1] - row0, MAXD);

  int v = lane & 31;
  bool hi = lane >= 32;
  int hh = v >> 3;  // head of channel v (m = MUL/H = 8)
  float accS = 0.f, acc0 = 0.f, acc1 = 0.f, acc2 = 0.f;

  if (deg > 0) {
    int iters = (deg + 3) >> 2;
    for (int it = 0; it < iters; ++it) {
      int sb = it * 4;
      int slot[4]; int sp[4];
#pragma unroll
      for (int k = 0; k < 4; k++) slot[k] = row0 + min(sb + k, deg - 1);
#pragma unroll
      for (int k = 0; k < 4; k++) sp[k] = srcc[slot[k]];
      float4 ya[4]; float sav[4]; float2 wj[4]; float s0[4], s1[4], s2[4];
#pragma unroll
      for (int k = 0; k < 4; k++) {
        sav[k] = (sb + k < deg) ? sa_in[(size_t)slot[k] * 4 + hh] : 0.f;  // OOB -> 0
        ya[k] = ((const float4*)ec)[slot[k]];
        wj[k] = ((const float2*)wm)[(size_t)slot[k] * 64 + (hi ? 32 : 0) + v];
        const float* nf = &node_f[(size_t)sp[k] * 128];
        if (!hi) { s0[k] = nf[v]; s1[k] = 0.f; s2[k] = 0.f; }
        else     { s0[k] = nf[32 + v * 3]; s1[k] = nf[33 + v * 3]; s2[k] = nf[34 + v * 3]; }
      }
#pragma unroll
      for (int k = 0; k < 4; k++) {
        float ys = ya[k].x, yv0 = ya[k].y, yv1 = ya[k].z, yv2 = ya[k].w;
        float sav_k = sav[k];
        if (!hi) {  // v0 -> s-ch v ; vv0 -> v-ch (u=v, d)
          accS += wj[k].x * s0[k] * ys * sav_k;
          float b = wj[k].y * s0[k] * sav_k;
          acc0 += b * yv0; acc1 += b * yv1; acc2 += b * yv2;
        } else {    // v1 -> s-ch 32+v ; vv1 -> v-ch (u=32+v, d)
          float dotv = s0[k] * yv0 + s1[k] * yv1 + s2[k] * yv2;
          accS += wj[k].x * dotv * INV3 * sav_k;
          float c = wj[k].y * ys * sav_k;
          acc0 += c * s0[k]; acc1 += c * s1[k]; acc2 += c * s2[k];
        }
      }
    }
  }
  // wave-private aggregation + fused output linear (weights from L2)
  {
    int us = hi ? 32 + v : v;
    aggv[wave][us]       = accS;
    aggv[wave][64 + us]  = acc0;
    aggv[wave][128 + us] = acc1;
    aggv[wave][192 + us] = acc2;
    const float* agg = aggv[wave];   // in-wave DS ordering: writes precede reads
#pragma unroll
    for (int rep = 0; rep < 2; ++rep) {
      int o = lane + rep * 64;
      float acc = 0.f;
      if (o < 32) {
#pragma unroll
        for (int u = 0; u < 64; u++) acc += agg[u] * Wls[u * 32 + o];
      } else {
        int i = o - 32, w2 = i / 3, d = i - 3 * w2;
        const float* av = &agg[64 + d * 64];
#pragma unroll
        for (int u = 0; u < 64; u++) acc += av[u] * Wlv[u * 32 + w2];
      }
      out[(size_t)n * 128 + o] = acc * INV_L;
    }
  }
}

// ---------------- host launcher ----------------
extern "C" void kernel_launch(void* const* d_in, const int* in_sizes, int n_in,
                              void* d_out, int out_size, void* d_ws, size_t ws_size,
                              hipStream_t stream) {
  const int*   esrc   = (const int*)d_in[0];
  const int*   edst   = (const int*)d_in[1];
  const float* xattr  = (const float*)d_in[2];
  const float* eattr  = (const float*)d_in[3];
  const float* cutoff = (const float*)d_in[4];
  const float* node_f = (const float*)d_in[5];
  const float* wk1    = (const float*)d_in[6];
  const float* bk1    = (const float*)d_in[7];
  const float* wk2    = (const float*)d_in[8];
  const float* wv1    = (const float*)d_in[9];
  const float* bv1    = (const float*)d_in[10];
  const float* wv2    = (const float*)d_in[11];
  const float* Wdot   = (const float*)d_in[12];
  const float* Wls    = (const float*)d_in[13];
  const float* Wlv    = (const float*)d_in[14];
  float* out = (float*)d_out;

  int E = in_sizes[0];
  int N = in_sizes[5] / 128;

  // workspace layout (~230 MB; wm reused for K-MLP then V-MLP):
  float* A    = (float*)d_ws;                 // N*1024 f32
  float* sa   = A + (size_t)N * 1024;         // E*4 f32
  float* xc   = sa + (size_t)E * 4;           // E*8 f32 (CSR-ordered xattr)
  float* ec   = xc + (size_t)E * 8;           // E*4 f32 (CSR-ordered eattr)
  float* cc   = ec + (size_t)E * 4;           // E f32   (CSR-ordered cutoff)
  int* srcc   = (int*)(cc + (size_t)E);       // E       (CSR-ordered esrc)
  int* counts = srcc + E;                     // N   (zeroed)
  int* cursor = counts + N;                   // N   (zeroed)
  int* dbin   = cursor + N;                   // 128 (zeroed)
  int* dcur   = dbin + 128;                   // 128 (zeroed)
  int* rowptr = dcur + 128;                   // N+1
  int* doff   = rowptr + (N + 1);             // 128
  int* nperm  = doff + 128;                   // N
  int* csr    = nperm + N;                    // E
  float* wm   = (float*)(csr + E);            // E*128 f32 (163.8 MB)

  k_zero<<<(2 * N + 256 + 255) / 256, 256, 0, stream>>>(counts, 2 * N + 256);
  k_hist<<<(E + 255) / 256, 256, 0, stream>>>(edst, counts, E);
  k_scan<<<1, 256, 0, stream>>>(counts, rowptr, N);
  k_fill<<<(E + 255) / 256, 256, 0, stream>>>(edst, rowptr, cursor, csr, E);
  k_dhist<<<(N + 255) / 256, 256, 0, stream>>>(rowptr, dbin, N);
  k_dscan<<<1, 64, 0, stream>>>(dbin, doff);
  k_dfill<<<(N + 255) / 256, 256, 0, stream>>>(rowptr, doff, dcur, nperm, N);
  k_gather<<<(E + 255) / 256, 256, 0, stream>>>(csr, esrc, xattr, eattr, cutoff,
                                                xc, ec, cc, srcc, E);
  k_nodeA<<<(N + 31) / 32, 256, 0, stream>>>(node_f, Wdot, A, N);

  int chunk = 512;                              // slots per k_mlp block
  int mgrid = (E + chunk - 1) / chunk;          // 625 blocks (~2.4/CU, resident)
  int nb = (N + 3) / 4;                         // one node per wave

  k_mlp<<<mgrid, 256, 0, stream>>>(xc, wk1, bk1, wk2, wm, E, chunk);
  k_att<<<nb, 256, 0, stream>>>(rowptr, nperm, srcc, ec, cc, node_f, wm, A, sa, N);
  k_mlp<<<mgrid, 256, 0, stream>>>(xc, wv1, bv1, wv2, wm, E, chunk);
  k_agg<<<nb, 256, 0, stream>>>(rowptr, nperm, srcc, ec, node_f, wm,
                                Wls, Wlv, sa, out, N);
}

// Round 10
// 875.345 us; speedup vs baseline: 1.3512x; 1.0880x over previous
//
#include <hip/hip_runtime.h>

// Equivariant graph attention (Transformer_41480794145180) — fp32 throughout.
//
// Pipeline (all on `stream`):
//   k_zero/k_hist/k_scan/k_fill : build CSR of edges grouped by dst node
//   k_dhist/k_dscan/k_dfill     : counting-sort nodes by degree (descending)
//   k_gather: permute xattr/eattr/cutoff/esrc into CSR slot order
//   k_nodeA : per-node A fragments (lane-contiguous layout)
//   k_mlp   : edge-parallel dense MLP (8->64->128) -> wm[slot][128];
//             xc read linearly; wq bank-conflict-free via XOR swizzle
//   k_att   : wave-per-node (degree-sorted): logits from wm -> folded reduce
//             -> expw -> z (regs) -> sa (CSR order)
//   k_mlp   : again with V weights, overwriting wm (buffer reuse)
//   k_agg   : wave-per-node: v-terms from wm * sa -> wave agg -> fused
//             output linear -> out
//
// R10 (R9 post-mortem: k_mlp stuck at VALU 35% / 289us; arithmetic shows the
// layer-2 weight reads wq[q][lane] have 16B lane stride -> 8-way LDS bank
// conflict (~2.9x, 1.14M SQ_LDS_BANK_CONFLICT) making the LDS pipe the
// bottleneck; plus 625 blocks vs 512 residency -> 22%-loaded second round):
//  - wq XOR-swizzle j -> j ^ ((j>>3)&7) (float4 granularity), applied at BOTH
//    staging and read: groups of 8 lanes hit 8 distinct bank groups.
//  - k_mlp grid = exactly 512 blocks, chunk = ceil(E/512): zero tail.

constexpr float INV3    = 0.57735026918962576f;  // 1/sqrt(3)
constexpr float INV_SQ8 = 0.35355339059327373f;  // 1/sqrt(N_BASIS=8)
constexpr float INV_HID = 0.125f;                // 1/sqrt(HID=64)
constexpr float INV_FAN = 0.015625f;             // 1/sqrt(4*32*32)
constexpr float INV_L   = 0.125f;                // 1/sqrt(2*MUL=64)
constexpr int   MAXD    = 128;                   // max in-degree (Poisson(32))

// jax.nn.gelu default (approximate=True, tanh form)
__device__ __forceinline__ float gelu_tanh(float x) {
  float u = 0.7978845608028654f * (x + 0.044715f * x * x * x);
  float e = __expf(2.0f * u);            // e=inf / e=0 limits are exact
  return x * (1.0f - 1.0f / (e + 1.0f)); // = 0.5x(1+tanh(u))
}

// ---------------- CSR build ----------------
__global__ void k_zero(int* __restrict__ p, int n) {
  int i = blockIdx.x * 256 + threadIdx.x;
  if (i < n) p[i] = 0;
}

__global__ void k_hist(const int* __restrict__ dst, int* __restrict__ cnt, int E) {
  int e = blockIdx.x * 256 + threadIdx.x;
  if (e < E) atomicAdd(&cnt[dst[e]], 1);
}

// single-block exclusive scan over N counts -> rowptr[0..N]
__global__ __launch_bounds__(256) void k_scan(const int* __restrict__ cnt,
                                              int* __restrict__ rowptr, int N) {
  __shared__ int wsum[4];
  __shared__ int woff[4];
  __shared__ int carry;
  int t = threadIdx.x, wave = t >> 6, lane = t & 63;
  if (t == 0) { carry = 0; rowptr[0] = 0; }
  __syncthreads();
  for (int base = 0; base < N; base += 256) {
    int i = base + t;
    int inc = (i < N) ? cnt[i] : 0;
#pragma unroll
    for (int off = 1; off < 64; off <<= 1) {
      int y = __shfl_up(inc, off, 64);
      if (lane >= off) inc += y;
    }
    if (lane == 63) wsum[wave] = inc;
    __syncthreads();
    if (t == 0) {
      int r = 0;
      for (int w = 0; w < 4; w++) { woff[w] = r; r += wsum[w]; }
    }
    __syncthreads();
    int incl = inc + woff[wave] + carry;
    if (i < N) rowptr[i + 1] = incl;
    __syncthreads();
    if (t == 255) carry = incl;  // padded lanes add 0, so this is the chunk total
    __syncthreads();
  }
}

__global__ void k_fill(const int* __restrict__ dst, const int* __restrict__ rowptr,
                       int* __restrict__ cursor, int* __restrict__ csr, int E) {
  int e = blockIdx.x * 256 + threadIdx.x;
  if (e < E) {
    int d = dst[e];
    int s = atomicAdd(&cursor[d], 1);
    csr[rowptr[d] + s] = e;
  }
}

// ---------------- degree counting sort (descending) ----------------
__global__ void k_dhist(const int* __restrict__ rowptr, int* __restrict__ dbin, int N) {
  int n = blockIdx.x * 256 + threadIdx.x;
  if (n < N) {
    int deg = rowptr[n + 1] - rowptr[n];
    atomicAdd(&dbin[min(deg, 127)], 1);
  }
}

__global__ void k_dscan(const int* __restrict__ dbin, int* __restrict__ doff) {
  if (threadIdx.x == 0 && blockIdx.x == 0) {
    int r = 0;
    for (int d = 127; d >= 0; --d) { doff[d] = r; r += dbin[d]; }
  }
}

__global__ void k_dfill(const int* __restrict__ rowptr, const int* __restrict__ doff,
                        int* __restrict__ dcur, int* __restrict__ nperm, int N) {
  int n = blockIdx.x * 256 + threadIdx.x;
  if (n < N) {
    int d = min(rowptr[n + 1] - rowptr[n], 127);
    int p = doff[d] + atomicAdd(&dcur[d], 1);
    nperm[p] = n;
  }
}

// permute edge arrays into CSR slot order (coalesced writes, random reads)
__global__ __launch_bounds__(256) void k_gather(
    const int* __restrict__ csr, const int* __restrict__ esrc,
    const float* __restrict__ xattr, const float* __restrict__ eattr,
    const float* __restrict__ cutoff,
    float* __restrict__ xc, float* __restrict__ ec, float* __restrict__ cc,
    int* __restrict__ srcc, int E) {
  int p = blockIdx.x * 256 + threadIdx.x;
  if (p >= E) return;
  int e = csr[p];
  srcc[p] = esrc[e];
  cc[p] = cutoff[e];
  ((float4*)ec)[p] = ((const float4*)eattr)[e];
  const float4* xs = (const float4*)xattr + (size_t)e * 2;
  float4* xd = (float4*)xc + (size_t)p * 2;
  xd[0] = xs[0]; xd[1] = xs[1];
}

// ---------------- per-node A precompute ----------------
// A layout per node (1024 f32), lane-contiguous:
//   A0[32][4] (v,h) | A1[32][4] | A2[32][4][3] (v,h,d) | A3[32][4][3]
__global__ __launch_bounds__(256) void k_nodeA(const float* __restrict__ node_f,
                                               const float* __restrict__ Wdot,
                                               float* __restrict__ A, int N) {
  __shared__ float Wd[16384];     // 64 KiB: W_dot[4][4][32][32]
  __shared__ float nfs[32 * 128]; // 16 KiB: 32 nodes' features
  int t = threadIdx.x;
  for (int i = t; i < 16384; i += 256) Wd[i] = Wdot[i];
  int n0 = blockIdx.x * 32;
  int nEnd = min(32, N - n0);
  for (int i = t; i < nEnd * 128; i += 256) nfs[i] = node_f[n0 * 128 + i];
  __syncthreads();
  for (int nn = 0; nn < nEnd; ++nn) {
    const float* nf = &nfs[nn * 128];
    float* An = &A[(n0 + nn) * 1024];
#pragma unroll
    for (int k = 0; k < 4; k++) {
      int o = t + k * 256;  // branch below is uniform per k (no divergence)
      float acc = 0.f;
      int idx;
      if (o < 256) {        // A0 / A1 : scalar q
        int term = o >> 7, h = (o >> 5) & 3, v = o & 31;
        const float* W = &Wd[term * 4096 + h * 1024 + v];
#pragma unroll
        for (int u = 0; u < 32; u++) acc += W[u * 32] * nf[u];
        idx = term * 128 + v * 4 + h;
      } else {              // A2 / A3 : vector q
        int r = o - 256;
        int term = r / 384;                 // 0,1 -> A2,A3
        int rr = r % 384;
        int h = rr / 96, q = rr % 96, v = q / 3, d = q - 3 * (q / 3);
        const float* W = &Wd[(term + 2) * 4096 + h * 1024 + v];
#pragma unroll
        for (int u = 0; u < 32; u++) acc += W[u * 32] * nf[32 + u * 3 + d];
        idx = 256 + term * 384 + v * 12 + h * 3 + d;
      }
      An[idx] = acc;
    }
  }
}

// ---------------- edge-parallel MLP precompute ----------------
// wm[slot][128] layout: [lo half: (row0[v],row2[v]) pairs, v=0..31]
//                       [hi half: (row1[v],row3[v]) pairs, v=0..31]
// Pre-scaled by INV_HID. Input xc read LINEARLY by slot (CSR order).
// wq column index XOR-swizzled (j -> j^((j>>3)&7), float4 granularity) so the
// per-lane 16B-stride weight reads are bank-conflict-free (both write & read).
__global__ __launch_bounds__(256) void k_mlp(
    const float* __restrict__ xc,      // E x 8, CSR slot order
    const float* __restrict__ w1, const float* __restrict__ b1,
    const float* __restrict__ w2,
    float* __restrict__ wm,            // E x 128, CSR slot order
    int E, int chunk)
{
  __shared__ __align__(16) float w1s[512];
  __shared__ float b1s[64];
  __shared__ __align__(16) float wq[16][128][4];  // wq[l/4][j_swz][l%4] = w2[l][j]
  __shared__ __align__(16) float Hs[4][4][64];    // wave-private

  int t = threadIdx.x;
  int wave = t >> 6, lane = t & 63;
  for (int i = t; i < 512; i += 256) w1s[i] = w1[i];
  if (t < 64) b1s[t] = b1[t];
  for (int i = t; i < 8192; i += 256) {
    int l = i >> 7, j = i & 127;
    int js = j ^ ((j >> 3) & 7);                  // swizzled column
    wq[l >> 2][js][l & 3] = w2[i];
  }
  __syncthreads();

  int base = blockIdx.x * chunk;
  int end = min(base + chunk, E);
  int v = lane & 31;
  bool hi = lane >= 32;
  // swizzled read columns for this lane's two outputs (j=lane, j=lane+64)
  int c0 = lane, c1 = lane + 64;
  int c0s = c0 ^ ((c0 >> 3) & 7);
  int c1s = c1 ^ ((c1 >> 3) & 7);

  for (int sb = base + wave * 4; sb < end; sb += 16) {
    int sl[4];
#pragma unroll
    for (int k = 0; k < 4; k++) sl[k] = min(sb + k, E - 1);
    float h[4];
#pragma unroll
    for (int k = 0; k < 4; k++) {
      const float4* xp = (const float4*)xc + (size_t)sl[k] * 2;  // linear stream
      float4 xa = xp[0], xb = xp[1];
      float acc = xa.x * w1s[lane]       + xa.y * w1s[64 + lane]
                + xa.z * w1s[128 + lane] + xa.w * w1s[192 + lane]
                + xb.x * w1s[256 + lane] + xb.y * w1s[320 + lane]
                + xb.z * w1s[384 + lane] + xb.w * w1s[448 + lane];
      h[k] = gelu_tanh(acc * INV_SQ8 + b1s[lane]);
    }
#pragma unroll
    for (int k = 0; k < 4; k++) Hs[wave][k][lane] = h[k];  // wave-private
    float a0[4] = {0, 0, 0, 0}, a1[4] = {0, 0, 0, 0};
#pragma unroll
    for (int q = 0; q < 16; q++) {
      float4 wA = *(const float4*)&wq[q][c0s][0];   // conflict-free (swizzled)
      float4 wB = *(const float4*)&wq[q][c1s][0];
#pragma unroll
      for (int k = 0; k < 4; k++) {
        float4 hq = *(const float4*)&Hs[wave][k][q * 4];  // uniform broadcast
        a0[k] += hq.x * wA.x + hq.y * wA.y + hq.z * wA.z + hq.w * wA.w;
        a1[k] += hq.x * wB.x + hq.y * wB.y + hq.z * wB.z + hq.w * wB.w;
      }
    }
#pragma unroll
    for (int k = 0; k < 4; k++) {
      if (sb + k < end) {
        float2 o = make_float2(a0[k] * INV_HID, a1[k] * INV_HID);
        ((float2*)wm)[(size_t)sl[k] * 64 + (hi ? 32 : 0) + v] = o;
      }
    }
  }
}

// ---------------- attention pass (wave-per-node, degree-sorted) ----------------
__global__ __launch_bounds__(256) void k_att(
    const int* __restrict__ rowptr,
    const int* __restrict__ nperm,     // degree-sorted node ids
    const int* __restrict__ srcc,      // E, CSR order
    const float* __restrict__ ec,      // E x 4, CSR order
    const float* __restrict__ cc,      // E, CSR order
    const float* __restrict__ node_f,  // N x 128
    const float* __restrict__ wm,      // E x 128 (K-MLP, INV_HID folded)
    const float* __restrict__ A,       // N x 1024 (lane-contiguous layout)
    float* __restrict__ sa_out,        // E x 4, CSR slot order
    int N)
{
  __shared__ float expws[4][MAXD][4];  // per-wave

  int t = threadIdx.x;
  int wave = t >> 6, lane = t & 63;
  int idx = blockIdx.x * 4 + wave;
  if (idx >= N) return;
  int n = nperm[idx];
  int row0 = rowptr[n];
  int deg = min(rowptr[n + 1] - row0, MAXD);
  if (deg <= 0) return;

  int v = lane & 31;
  bool hi = lane >= 32;
  int kk = (lane >> 2) & 3;

  // A fragments in registers
  float aS[4], aV[12];
  {
    const float* Ab = A + (size_t)n * 1024;
    const float* ps = Ab + (hi ? 128 : 0) + v * 4;
    float4 t0 = *(const float4*)ps;
    aS[0] = t0.x; aS[1] = t0.y; aS[2] = t0.z; aS[3] = t0.w;
    const float* pv = Ab + (hi ? 640 : 256) + v * 12;
    float4 u0 = *(const float4*)pv;
    float4 u1 = *(const float4*)(pv + 4);
    float4 u2 = *(const float4*)(pv + 8);
    aV[0] = u0.x; aV[1] = u0.y; aV[2]  = u0.z; aV[3]  = u0.w;
    aV[4] = u1.x; aV[5] = u1.y; aV[6]  = u1.z; aV[7]  = u1.w;
    aV[8] = u2.x; aV[9] = u2.y; aV[10] = u2.z; aV[11] = u2.w;
  }

  int iters = (deg + 3) >> 2;
  float zacc = 0.f;  // lanes 0..15: partial z for (kk, h2=lane&3)

  for (int it = 0; it < iters; ++it) {
    int sb = it * 4;
    int slot[4]; int sp[4];
#pragma unroll
    for (int k = 0; k < 4; k++) slot[k] = row0 + min(sb + k, deg - 1);
#pragma unroll
    for (int k = 0; k < 4; k++) sp[k] = srcc[slot[k]];
    float4 ya[4]; float cf[4]; float2 wj[4]; float s0[4], s1[4], s2[4];
#pragma unroll
    for (int k = 0; k < 4; k++) {
      ya[k] = ((const float4*)ec)[slot[k]];
      cf[k] = (sb + k < deg) ? cc[slot[k]] : 0.f;   // OOB -> expw 0
      wj[k] = ((const float2*)wm)[(size_t)slot[k] * 64 + (hi ? 32 : 0) + v];
      const float* nf = &node_f[(size_t)sp[k] * 128];
      if (!hi) { s0[k] = nf[v]; s1[k] = 0.f; s2[k] = 0.f; }
      else     { s0[k] = nf[32 + v * 3]; s1[k] = nf[33 + v * 3]; s2[k] = nf[34 + v * 3]; }
    }
    // attention logits; p[m], m = k*4 + h2
    float p[16];
#pragma unroll
    for (int k = 0; k < 4; k++) {
      float ys = ya[k].x, yv0 = ya[k].y, yv1 = ya[k].z, yv2 = ya[k].w;
      if (!hi) {  // lanes 0..31: k0 (row 0) + kv0 (row 2)
        float k0 = wj[k].x * s0[k] * ys;
        float kb = INV3 * wj[k].y * s0[k];
#pragma unroll
        for (int h2 = 0; h2 < 4; h2++)
          p[k * 4 + h2] = aS[h2] * k0 +
              kb * (aV[h2 * 3] * yv0 + aV[h2 * 3 + 1] * yv1 + aV[h2 * 3 + 2] * yv2);
      } else {    // lanes 32..63: k1 (row 1) + kv1 (row 3)
        float dotv = s0[k] * yv0 + s1[k] * yv1 + s2[k] * yv2;
        float k1 = wj[k].x * dotv * INV3;
        float kc = INV3 * wj[k].y * ys;
#pragma unroll
        for (int h2 = 0; h2 < 4; h2++)
          p[k * 4 + h2] = aS[h2] * k1 +
              kc * (aV[h2 * 3] * s0[k] + aV[h2 * 3 + 1] * s1[k] + aV[h2 * 3 + 2] * s2[k]);
      }
    }
    // folded butterfly: 16 per-lane values -> full sums keyed by lane&15
    bool fb0 = (lane & 1) != 0;
    float q8[8];
#pragma unroll
    for (int j = 0; j < 8; j++) {
      float a = p[2 * j], b = p[2 * j + 1];
      float keep = fb0 ? b : a, send = fb0 ? a : b;
      q8[j] = keep + __shfl_xor(send, 1, 64);
    }
    bool fb1 = (lane & 2) != 0;
    float r4[4];
#pragma unroll
    for (int j = 0; j < 4; j++) {
      float a = q8[2 * j], b = q8[2 * j + 1];
      float keep = fb1 ? b : a, send = fb1 ? a : b;
      r4[j] = keep + __shfl_xor(send, 2, 64);
    }
    bool fb2 = (lane & 4) != 0;
    float s2v[2];
#pragma unroll
    for (int j = 0; j < 2; j++) {
      float a = r4[2 * j], b = r4[2 * j + 1];
      float keep = fb2 ? b : a, send = fb2 ? a : b;
      s2v[j] = keep + __shfl_xor(send, 4, 64);
    }
    bool fb3 = (lane & 8) != 0;
    float w;
    {
      float a = s2v[0], b = s2v[1];
      float keep = fb3 ? b : a, send = fb3 ? a : b;
      w = keep + __shfl_xor(send, 8, 64);
    }
    w += __shfl_xor(w, 16, 64);
    w += __shfl_xor(w, 32, 64);
    // lane l holds sum for edge (l>>2)&3, head l&3
    float cA = (lane & 4) ? cf[1] : cf[0];
    float cB = (lane & 4) ? cf[3] : cf[2];
    float cfs = (lane & 8) ? cB : cA;
    int slotw = sb + kk;
    float ex = cfs * __expf(w * INV_FAN);
    if (lane < 16 && slotw < deg) {
      expws[wave][slotw][lane & 3] = ex;
      zacc += ex;
    }
  }
  // z reduce: lanes 0..15 hold partials (kk, h2=lane&3); sum over kk
  float zr = zacc;
  zr += __shfl_xor(zr, 4, 64);
  zr += __shfl_xor(zr, 8, 64);
  float zf = __shfl(zr, lane & 3, 64);
  zf = (zf == 0.f) ? 1.f : zf;
  for (int i = lane; i < deg * 4; i += 64) {
    int slot = i >> 2;  // i&3 == lane&3
    float alpha = expws[wave][slot][lane & 3] / zf;
    sa_out[(size_t)(row0 + slot) * 4 + (lane & 3)] = sqrtf(fmaxf(alpha, 0.f));
  }
}

// ---------------- aggregation pass + output linear ----------------
__global__ __launch_bounds__(256) void k_agg(
    const int* __restrict__ rowptr,
    const int* __restrict__ nperm,
    const int* __restrict__ srcc,
    const float* __restrict__ ec,
    const float* __restrict__ node_f,
    const float* __restrict__ wm,      // E x 128 (V-MLP, INV_HID folded)
    const float* __restrict__ Wls, const float* __restrict__ Wlv,  // 64x32 each
    const float* __restrict__ sa_in,   // E x 4, CSR slot order
    float* __restrict__ out,           // N x 128
    int N)
{
  __shared__ float aggv[4][256];  // [wave][ch']: ch'=u (s) | 64+d*64+u (v)

  int t = threadIdx.x;
  int wave = t >> 6, lane = t & 63;
  int idx = blockIdx.x * 4 + wave;
  if (idx >= N) return;
  int n = nperm[idx];
  int row0 = rowptr[n];
  int deg = min(rowptr[n + 1] - row0, MAXD);

  int v = lane & 31;
  bool hi = lane >= 32;
  int hh = v >> 3;  // head of channel v (m = MUL/H = 8)
  float accS = 0.f, acc0 = 0.f, acc1 = 0.f, acc2 = 0.f;

  if (deg > 0) {
    int iters = (deg + 3) >> 2;
    for (int it = 0; it < iters; ++it) {
      int sb = it * 4;
      int slot[4]; int sp[4];
#pragma unroll
      for (int k = 0; k < 4; k++) slot[k] = row0 + min(sb + k, deg - 1);
#pragma unroll
      for (int k = 0; k < 4; k++) sp[k] = srcc[slot[k]];
      float4 ya[4]; float sav[4]; float2 wj[4]; float s0[4], s1[4], s2[4];
#pragma unroll
      for (int k = 0; k < 4; k++) {
        sav[k] = (sb + k < deg) ? sa_in[(size_t)slot[k] * 4 + hh] : 0.f;  // OOB -> 0
        ya[k] = ((const float4*)ec)[slot[k]];
        wj[k] = ((const float2*)wm)[(size_t)slot[k] * 64 + (hi ? 32 : 0) + v];
        const float* nf = &node_f[(size_t)sp[k] * 128];
        if (!hi) { s0[k] = nf[v]; s1[k] = 0.f; s2[k] = 0.f; }
        else     { s0[k] = nf[32 + v * 3]; s1[k] = nf[33 + v * 3]; s2[k] = nf[34 + v * 3]; }
      }
#pragma unroll
      for (int k = 0; k < 4; k++) {
        float ys = ya[k].x, yv0 = ya[k].y, yv1 = ya[k].z, yv2 = ya[k].w;
        float sav_k = sav[k];
        if (!hi) {  // v0 -> s-ch v ; vv0 -> v-ch (u=v, d)
          accS += wj[k].x * s0[k] * ys * sav_k;
          float b = wj[k].y * s0[k] * sav_k;
          acc0 += b * yv0; acc1 += b * yv1; acc2 += b * yv2;
        } else {    // v1 -> s-ch 32+v ; vv1 -> v-ch (u=32+v, d)
          float dotv = s0[k] * yv0 + s1[k] * yv1 + s2[k] * yv2;
          accS += wj[k].x * dotv * INV3 * sav_k;
          float c = wj[k].y * ys * sav_k;
          acc0 += c * s0[k]; acc1 += c * s1[k]; acc2 += c * s2[k];
        }
      }
    }
  }
  // wave-private aggregation + fused output linear (weights from L2)
  {
    int us = hi ? 32 + v : v;
    aggv[wave][us]       = accS;
    aggv[wave][64 + us]  = acc0;
    aggv[wave][128 + us] = acc1;
    aggv[wave][192 + us] = acc2;
    const float* agg = aggv[wave];   // in-wave DS ordering: writes precede reads
#pragma unroll
    for (int rep = 0; rep < 2; ++rep) {
      int o = lane + rep * 64;
      float acc = 0.f;
      if (o < 32) {
#pragma unroll
        for (int u = 0; u < 64; u++) acc += agg[u] * Wls[u * 32 + o];
      } else {
        int i = o - 32, w2 = i / 3, d = i - 3 * w2;
        const float* av = &agg[64 + d * 64];
#pragma unroll
        for (int u = 0; u < 64; u++) acc += av[u] * Wlv[u * 32 + w2];
      }
      out[(size_t)n * 128 + o] = acc * INV_L;
    }
  }
}

// ---------------- host launcher ----------------
extern "C" void kernel_launch(void* const* d_in, const int* in_sizes, int n_in,
                              void* d_out, int out_size, void* d_ws, size_t ws_size,
                              hipStream_t stream) {
  const int*   esrc   = (const int*)d_in[0];
  const int*   edst   = (const int*)d_in[1];
  const float* xattr  = (const float*)d_in[2];
  const float* eattr  = (const float*)d_in[3];
  const float* cutoff = (const float*)d_in[4];
  const float* node_f = (const float*)d_in[5];
  const float* wk1    = (const float*)d_in[6];
  const float* bk1    = (const float*)d_in[7];
  const float* wk2    = (const float*)d_in[8];
  const float* wv1    = (const float*)d_in[9];
  const float* bv1    = (const float*)d_in[10];
  const float* wv2    = (const float*)d_in[11];
  const float* Wdot   = (const float*)d_in[12];
  const float* Wls    = (const float*)d_in[13];
  const float* Wlv    = (const float*)d_in[14];
  float* out = (float*)d_out;

  int E = in_sizes[0];
  int N = in_sizes[5] / 128;

  // workspace layout (~230 MB; wm reused for K-MLP then V-MLP):
  float* A    = (float*)d_ws;                 // N*1024 f32
  float* sa   = A + (size_t)N * 1024;         // E*4 f32
  float* xc   = sa + (size_t)E * 4;           // E*8 f32 (CSR-ordered xattr)
  float* ec   = xc + (size_t)E * 8;           // E*4 f32 (CSR-ordered eattr)
  float* cc   = ec + (size_t)E * 4;           // E f32   (CSR-ordered cutoff)
  int* srcc   = (int*)(cc + (size_t)E);       // E       (CSR-ordered esrc)
  int* counts = srcc + E;                     // N   (zeroed)
  int* cursor = counts + N;                   // N   (zeroed)
  int* dbin   = cursor + N;                   // 128 (zeroed)
  int* dcur   = dbin + 128;                   // 128 (zeroed)
  int* rowptr = dcur + 128;                   // N+1
  int* doff   = rowptr + (N + 1);             // 128
  int* nperm  = doff + 128;                   // N
  int* csr    = nperm + N;                    // E
  float* wm   = (float*)(csr + E);            // E*128 f32 (163.8 MB)

  k_zero<<<(2 * N + 256 + 255) / 256, 256, 0, stream>>>(counts, 2 * N + 256);
  k_hist<<<(E + 255) / 256, 256, 0, stream>>>(edst, counts, E);
  k_scan<<<1, 256, 0, stream>>>(counts, rowptr, N);
  k_fill<<<(E + 255) / 256, 256, 0, stream>>>(edst, rowptr, cursor, csr, E);
  k_dhist<<<(N + 255) / 256, 256, 0, stream>>>(rowptr, dbin, N);
  k_dscan<<<1, 64, 0, stream>>>(dbin, doff);
  k_dfill<<<(N + 255) / 256, 256, 0, stream>>>(rowptr, doff, dcur, nperm, N);
  k_gather<<<(E + 255) / 256, 256, 0, stream>>>(csr, esrc, xattr, eattr, cutoff,
                                                xc, ec, cc, srcc, E);
  k_nodeA<<<(N + 31) / 32, 256, 0, stream>>>(node_f, Wdot, A, N);

  int mgrid = 512;                              // exactly the residency: no tail
  int chunk = (E + mgrid - 1) / mgrid;          // equal work per block
  int nb = (N + 3) / 4;                         // one node per wave

  k_mlp<<<mgrid, 256, 0, stream>>>(xc, wk1, bk1, wk2, wm, E, chunk);
  k_att<<<nb, 256, 0, stream>>>(rowptr, nperm, srcc, ec, cc, node_f, wm, A, sa, N);
  k_mlp<<<mgrid, 256, 0, stream>>>(xc, wv1, bv1, wv2, wm, E, chunk);
  k_agg<<<nb, 256, 0, stream>>>(rowptr, nperm, srcc, ec, node_f, wm,
                                Wls, Wlv, sa, out, N);
}